// Round 5
// baseline (294.082 us; speedup 1.0000x reference)
//
#include <hip/hip_runtime.h>
#include <stdint.h>

#define D_MODEL 1024
#define SEQ 2048
#define BATCH 4
#define NH 16
#define DK 64

typedef float f32x4 __attribute__((ext_vector_type(4)));
typedef float f32x16 __attribute__((ext_vector_type(16)));
typedef __bf16 bf16x8 __attribute__((ext_vector_type(8)));
typedef unsigned short us4v __attribute__((ext_vector_type(4)));

__device__ __forceinline__ unsigned short f2bf(float f) {
  union { float f; unsigned u; } x; x.f = f;
  unsigned r = x.u + 0x7FFFu + ((x.u >> 16) & 1u);  // RNE
  return (unsigned short)(r >> 16);
}

// async global->LDS, 16B per lane (GEMM staging only)
__device__ __forceinline__ void gll16(const void* g, void* l) {
  __builtin_amdgcn_global_load_lds(
      (__attribute__((address_space(1))) void*)g,
      (__attribute__((address_space(3))) void*)l, 16, 0, 0);
}

// packed f32x2 -> bf16x2 (RNE), one VALU op
__device__ __forceinline__ int cvtpk(float lo, float hi) {
  int r;
  asm("v_cvt_pk_bf16_f32 %0, %1, %2" : "=v"(r) : "v"(lo), "v"(hi));
  return r;
}
// v_permlane32_swap_b32: a[32:63] <-> b[0:31]. ONLY safe when a and b are
// provably-distinct registers (e.g. distinct asm outputs) — a self-swap of a
// copied value can be register-coalesced into v_permlane32_swap v5,v5 (R3 bug).
__device__ __forceinline__ void pl32swap(int& a, int& b) {
  asm volatile("v_permlane32_swap_b32 %0, %1" : "+v"(a), "+v"(b));
}

// ---------------------------------------------------------------------------
// fp32 -> bf16 convert (vectorized float4 -> 4x bf16)
// ---------------------------------------------------------------------------
__global__ void cvtbf(const float* __restrict__ in, unsigned short* __restrict__ out, const int n) {
  const int t = blockIdx.x * blockDim.x + threadIdx.x;
  const int stride = gridDim.x * blockDim.x;
  for (int i = t * 4; i < n; i += stride * 4) {
    const float4 v = *(const float4*)&in[i];
    us4v o;
    o[0] = f2bf(v.x); o[1] = f2bf(v.y); o[2] = f2bf(v.z); o[3] = f2bf(v.w);
    *(us4v*)&out[i] = o;
  }
}

// ---------------------------------------------------------------------------
// weight transpose + convert: W[k][n] fp32 -> Wt[n][k] bf16   (1024x1024, x4)
// ---------------------------------------------------------------------------
__global__ void wtrans(const float* __restrict__ W0, const float* __restrict__ W1,
                       const float* __restrict__ W2, const float* __restrict__ W3,
                       unsigned short* __restrict__ T0, unsigned short* __restrict__ T1,
                       unsigned short* __restrict__ T2, unsigned short* __restrict__ T3) {
  __shared__ float t[32][33];
  const int z = blockIdx.z;
  const float* W = (z == 0) ? W0 : (z == 1) ? W1 : (z == 2) ? W2 : W3;
  unsigned short* T = (z == 0) ? T0 : (z == 1) ? T1 : (z == 2) ? T2 : T3;
  const int n0 = blockIdx.x * 32, k0 = blockIdx.y * 32;
  const int tx = threadIdx.x, ty = threadIdx.y;  // 32 x 8
#pragma unroll
  for (int i = 0; i < 4; ++i)
    t[ty + 8 * i][tx] = W[(size_t)(k0 + ty + 8 * i) * D_MODEL + n0 + tx];
  __syncthreads();
#pragma unroll
  for (int i = 0; i < 4; ++i)
    T[(size_t)(n0 + ty + 8 * i) * D_MODEL + k0 + tx] = f2bf(t[tx][ty + 8 * i]);
}

// ---------------------------------------------------------------------------
// bf16 GEMM: C[M=8192][N=1024] = A[M][K=1024] @ Wt[N][K]^T + bias
// 128x128 tile, BK=64, 4 waves (2x2 of 64x64), mfma_f32_16x16x32_bf16.
// mode 0: out bf16 [b,h,s,d] (Q,K); mode 1: out bf16 [b,h,d,s] (V^T);
// mode 2: out fp32 [m][n] (final projection)
// ---------------------------------------------------------------------------
__global__ __launch_bounds__(256) void gemm128(
    const unsigned short* __restrict__ A, const unsigned short* __restrict__ Bt,
    const float* __restrict__ bias, unsigned short* __restrict__ outb,
    float* __restrict__ outf, const int mode) {
  __shared__ __align__(16) unsigned short Alds[128 * 64];
  __shared__ __align__(16) unsigned short Blds[128 * 64];
  const int tid = threadIdx.x;
  const int lane = tid & 63;
  const int w = tid >> 6;
  const int wr = w >> 1, wc = w & 1;
  const int m0 = blockIdx.y * 128, n0 = blockIdx.x * 128;
  const int srow = tid >> 3, sslot = tid & 7;

  f32x4 acc[4][4] = {};

  for (int kk = 0; kk < D_MODEL / 64; ++kk) {
    __syncthreads();
#pragma unroll
    for (int i = 0; i < 4; ++i) {
      const int r = srow + 32 * i;
      const int gc = kk * 64 + ((sslot ^ (r & 7)) << 3);
      gll16(A + (size_t)(m0 + r) * D_MODEL + gc, &Alds[tid * 8 + i * 2048]);
      gll16(Bt + (size_t)(n0 + r) * D_MODEL + gc, &Blds[tid * 8 + i * 2048]);
    }
    __syncthreads();
#pragma unroll
    for (int kf = 0; kf < 2; ++kf) {
      const int sb = kf * 4 + (lane >> 4);
      bf16x8 a[4], b[4];
#pragma unroll
      for (int m = 0; m < 4; ++m) {
        const int row = wr * 64 + m * 16 + (lane & 15);
        a[m] = *(const bf16x8*)&Alds[row * 64 + ((sb ^ (row & 7)) << 3)];
      }
#pragma unroll
      for (int n = 0; n < 4; ++n) {
        const int row = wc * 64 + n * 16 + (lane & 15);
        b[n] = *(const bf16x8*)&Blds[row * 64 + ((sb ^ (row & 7)) << 3)];
      }
#pragma unroll
      for (int m = 0; m < 4; ++m)
#pragma unroll
        for (int n = 0; n < 4; ++n)
          acc[m][n] = __builtin_amdgcn_mfma_f32_16x16x32_bf16(a[m], b[n], acc[m][n], 0, 0, 0);
    }
  }

#pragma unroll
  for (int m = 0; m < 4; ++m) {
    const int rb = m0 + wr * 64 + m * 16 + ((lane >> 4) << 2);
#pragma unroll
    for (int n = 0; n < 4; ++n) {
      const int col = n0 + wc * 64 + n * 16 + (lane & 15);
      const float bv = bias[col];
#pragma unroll
      for (int j = 0; j < 4; ++j) {
        const int row = rb + j;
        const float v = acc[m][n][j] + bv;
        if (mode == 2) {
          outf[(size_t)row * D_MODEL + col] = v;
        } else {
          const int b_ = row >> 11, s_ = row & (SEQ - 1);
          const int h_ = col >> 6, d_ = col & (DK - 1);
          size_t idx;
          if (mode == 0) idx = (((size_t)(b_ * NH + h_)) * SEQ + s_) * DK + d_;
          else           idx = (((size_t)(b_ * NH + h_)) * DK + d_) * SEQ + s_;
          outb[idx] = f2bf(v);
        }
      }
    }
  }
}

// ---------------------------------------------------------------------------
// causal flash attention, 1-wave blocks, NO LDS / NO barriers.
// Block = (bh, qstrip): one wave owns 32 q-rows (lane&31 -> q-row).
// Swapped ops: S^T = K·Q^T (K as A-operand, per-lane row -> plain global
// loads from L2-resident K), P in registers, O^T += V^T·P^T from Vt [d][s].
// Softmax lane-local + __shfl_xor(32) cross-half reduce; defer-max THR=8.
// Latency hiding via TLP; heavy q-strips dispatched first; blockIdx.x = bh
// so bh%8 groups each head's K/V onto one XCD L2.
// ---------------------------------------------------------------------------
__global__ __launch_bounds__(64, 4) void attn1w(
    const unsigned short* __restrict__ Q, const unsigned short* __restrict__ K,
    const unsigned short* __restrict__ Vt, unsigned short* __restrict__ O) {
  const int lane = threadIdx.x;
  const int lq = lane & 31, hi = lane >> 5;
  const int bh = blockIdx.x;
  const int qtw = 63 - (int)blockIdx.y;  // heavy strips first
  const size_t qkbase = (size_t)bh * SEQ * DK;
  const size_t vbase = (size_t)bh * DK * SEQ;
  const int qw0 = qtw * 32;
  const int qg = qw0 + lq;  // this lane's q-row
  const int b_ = bh >> 4, h_ = bh & (NH - 1);

  // Q as B-operand frags: col=lane&31 -> q, k = hi*8 + ks*16 + e.
  // Pre-scaled by 1/sqrt(DK)=0.125 (power of 2 -> exact in bf16).
  bf16x8 qb[4];
  {
    const unsigned short* qp = Q + qkbase + (size_t)qg * DK + hi * 8;
#pragma unroll
    for (int ks = 0; ks < 4; ++ks) {
      qb[ks] = *(const bf16x8*)(qp + ks * 16);
#pragma unroll
      for (int e = 0; e < 8; ++e)
        qb[ks][e] = (__bf16)((float)qb[ks][e] * 0.125f);
    }
  }

  float m = -3e38f, l = 0.f;
  f32x16 o0 = {}, o1 = {};

  const int nphase = (qtw + 2) >> 1;
  for (int jt = 0; jt < nphase; ++jt) {
    const int kv0 = jt * 64;

    // K fragments straight from global (L2): rows kv0+lq, kv0+32+lq
    const unsigned short* kp0 = K + qkbase + (size_t)(kv0 + lq) * DK + hi * 8;
    const unsigned short* kp1 = kp0 + 32 * DK;
    bf16x8 ka0[4], ka1[4];
#pragma unroll
    for (int ks = 0; ks < 4; ++ks) {
      ka0[ks] = *(const bf16x8*)(kp0 + ks * 16);
      ka1[ks] = *(const bf16x8*)(kp1 + ks * 16);
    }

    // S^T = K·Q^T : st0 = kv0..+31, st1 = kv0+32..+63 (cols = 32 q's)
    f32x16 st0 = {}, st1 = {};
    __builtin_amdgcn_s_setprio(1);
#pragma unroll
    for (int ks = 0; ks < 4; ++ks) {
      st0 = __builtin_amdgcn_mfma_f32_32x32x16_bf16(ka0[ks], qb[ks], st0, 0, 0, 0);
      st1 = __builtin_amdgcn_mfma_f32_32x32x16_bf16(ka1[ks], qb[ks], st1, 0, 0, 0);
    }
    __builtin_amdgcn_s_setprio(0);

    // V fragments (issue before softmax; latency hides under VALU work)
    const unsigned short* vp0 = Vt + vbase + (size_t)lq * SEQ + kv0 + hi * 8;
    const unsigned short* vp1 = vp0 + 32 * SEQ;
    bf16x8 va0[4], va1[4];
#pragma unroll
    for (int ks = 0; ks < 4; ++ks) {
      va0[ks] = *(const bf16x8*)(vp0 + ks * 16);
      va1[ks] = *(const bf16x8*)(vp1 + ks * 16);
    }

    // causal mask: kv = kv0 + kvb*32 + (r&3)+8*(r>>2)+4*hi  vs  q-row qg
    if (jt == nphase - 1) {
      const int rb = kv0 + 4 * hi - qg;
#pragma unroll
      for (int r = 0; r < 16; ++r) {
        const int crow0 = (r & 3) + 8 * (r >> 2);
        if (crow0 + rb > 0)      st0[r] = -3e38f;
        if (crow0 + 32 + rb > 0) st1[r] = -3e38f;
      }
    }

    // row max: lane-local tree + one cross-half exchange (verified R2 path)
    float tmax[8];
#pragma unroll
    for (int r = 0; r < 8; ++r)
      tmax[r] = fmaxf(fmaxf(st0[r], st0[r + 8]), fmaxf(st1[r], st1[r + 8]));
    float mx = fmaxf(fmaxf(fmaxf(tmax[0], tmax[1]), fmaxf(tmax[2], tmax[3])),
                     fmaxf(fmaxf(tmax[4], tmax[5]), fmaxf(tmax[6], tmax[7])));
    mx = fmaxf(mx, __shfl_xor(mx, 32));

    // defer-max (T13, THR=8): skip rescale when max barely grew
    if (__any((int)(mx > m + 8.0f))) {
      const float mnew = fmaxf(m, mx);
      const float alpha = exp2f((m - mnew) * 1.44269504f);
      m = mnew;
      l *= alpha;
#pragma unroll
      for (int r = 0; r < 16; ++r) { o0[r] *= alpha; o1[r] *= alpha; }
    }

    // exp (P kept in st regs, bounded by e^8 under defer)
    const float ml = m * 1.44269504f;
#pragma unroll
    for (int r = 0; r < 16; ++r) {
      st0[r] = exp2f(__builtin_fmaf(st0[r], 1.44269504f, -ml));
      st1[r] = exp2f(__builtin_fmaf(st1[r], 1.44269504f, -ml));
    }

    // row sum: tree + cross-half
    float tsum[8];
#pragma unroll
    for (int r = 0; r < 8; ++r)
      tsum[r] = (st0[r] + st0[r + 8]) + (st1[r] + st1[r + 8]);
    float rs = ((tsum[0] + tsum[1]) + (tsum[2] + tsum[3])) +
               ((tsum[4] + tsum[5]) + (tsum[6] + tsum[7]));
    rs += __shfl_xor(rs, 32);
    l += rs;

    // P -> bf16 B-frags via cvt_pk + permlane32_swap (T12; operands here are
    // distinct asm outputs -> no aliasing hazard)
    bf16x8 pb[4];
#pragma unroll
    for (int ks = 0; ks < 4; ++ks) {
      const int base = (ks & 1) * 8;
      float p0, p1, p2, p3, p4, p5, p6, p7;
      if (ks < 2) {
        p0 = st0[base + 0]; p1 = st0[base + 1]; p2 = st0[base + 2]; p3 = st0[base + 3];
        p4 = st0[base + 4]; p5 = st0[base + 5]; p6 = st0[base + 6]; p7 = st0[base + 7];
      } else {
        p0 = st1[base + 0]; p1 = st1[base + 1]; p2 = st1[base + 2]; p3 = st1[base + 3];
        p4 = st1[base + 4]; p5 = st1[base + 5]; p6 = st1[base + 6]; p7 = st1[base + 7];
      }
      int a0 = cvtpk(p0, p1), a1 = cvtpk(p2, p3);
      int a2 = cvtpk(p4, p5), a3 = cvtpk(p6, p7);
      pl32swap(a0, a2);
      pl32swap(a1, a3);
      union { int i[4]; bf16x8 v; } u;
      u.i[0] = a0; u.i[1] = a1; u.i[2] = a2; u.i[3] = a3;
      pb[ks] = u.v;
    }

    // O^T += V^T·P^T
    __builtin_amdgcn_s_setprio(1);
#pragma unroll
    for (int ks = 0; ks < 4; ++ks) {
      o0 = __builtin_amdgcn_mfma_f32_32x32x16_bf16(va0[ks], pb[ks], o0, 0, 0, 0);
      o1 = __builtin_amdgcn_mfma_f32_32x32x16_bf16(va1[ks], pb[ks], o1, 0, 0, 0);
    }
    __builtin_amdgcn_s_setprio(0);
  }

  // epilogue: O[b*s][h*64+d]; lane owns q-row qg; o rows are d.
  const float rl = 1.0f / l;
  unsigned short* orow = O + (size_t)(b_ * SEQ + qg) * D_MODEL + h_ * DK;
#pragma unroll
  for (int g = 0; g < 4; ++g) {
    us4v pk0, pk1;
#pragma unroll
    for (int j = 0; j < 4; ++j) {
      pk0[j] = f2bf(o0[4 * g + j] * rl);
      pk1[j] = f2bf(o1[4 * g + j] * rl);
    }
    const int d0 = 8 * g + 4 * hi;
    *(us4v*)&orow[d0] = pk0;
    *(us4v*)&orow[32 + d0] = pk1;
  }
}

// ---------------------------------------------------------------------------
extern "C" void kernel_launch(void* const* d_in, const int* in_sizes, int n_in,
                              void* d_out, int out_size, void* d_ws, size_t ws_size,
                              hipStream_t stream) {
  const float* ctx = (const float*)d_in[0];
  const float* val = (const float*)d_in[1];
  // d_in[2] = mask: statically causal triu(k=1); handled analytically.
  const float* Wq = (const float*)d_in[3];
  const float* bq = (const float*)d_in[4];
  const float* Wk = (const float*)d_in[5];
  const float* bk = (const float*)d_in[6];
  const float* Wv = (const float*)d_in[7];
  const float* bv = (const float*)d_in[8];
  const float* Wo = (const float*)d_in[9];
  const float* bo = (const float*)d_in[10];

  unsigned short* ws = (unsigned short*)d_ws;
  const size_t XSZ = (size_t)BATCH * SEQ * D_MODEL;  // 8388608
  const size_t WSZ = (size_t)D_MODEL * D_MODEL;      // 1048576
  unsigned short* Xc  = ws;
  unsigned short* Xv  = Xc + XSZ;
  unsigned short* Wqt = Xv + XSZ;
  unsigned short* Wkt = Wqt + WSZ;
  unsigned short* Wvt = Wkt + WSZ;
  unsigned short* Wot = Wvt + WSZ;
  unsigned short* Qb  = Wot + WSZ;
  unsigned short* Kb  = Qb + XSZ;
  unsigned short* Vtb = Kb + XSZ;
  unsigned short* Ob  = Vtb + XSZ;

  cvtbf<<<1024, 256, 0, stream>>>(ctx, Xc, (int)XSZ);
  cvtbf<<<1024, 256, 0, stream>>>(val, Xv, (int)XSZ);
  wtrans<<<dim3(32, 32, 4), dim3(32, 8), 0, stream>>>(Wq, Wk, Wv, Wo, Wqt, Wkt, Wvt, Wot);

  dim3 gg(D_MODEL / 128, BATCH * SEQ / 128);  // (8, 64)
  gemm128<<<gg, 256, 0, stream>>>(Xc, Wqt, bq, Qb, nullptr, 0);
  gemm128<<<gg, 256, 0, stream>>>(Xc, Wkt, bk, Kb, nullptr, 0);
  gemm128<<<gg, 256, 0, stream>>>(Xv, Wvt, bv, Vtb, nullptr, 1);

  // 1-wave blocks: x = bh (64) so bh%8 -> XCD locality; y = q-strip, heavy first
  attn1w<<<dim3(BATCH * NH, 64), 64, 0, stream>>>(Qb, Kb, Vtb, Ob);

  gemm128<<<gg, 256, 0, stream>>>(Ob, Wot, bo, nullptr, (float*)d_out, 2);
}

// Round 6
// 215.902 us; speedup vs baseline: 1.3621x; 1.3621x over previous
//
#include <hip/hip_runtime.h>
#include <stdint.h>

#define D_MODEL 1024
#define SEQ 2048
#define BATCH 4
#define NH 16
#define DK 64

typedef float f32x4 __attribute__((ext_vector_type(4)));
typedef float f32x16 __attribute__((ext_vector_type(16)));
typedef __bf16 bf16x8 __attribute__((ext_vector_type(8)));
typedef unsigned short us4v __attribute__((ext_vector_type(4)));

__device__ __forceinline__ unsigned short f2bf(float f) {
  union { float f; unsigned u; } x; x.f = f;
  unsigned r = x.u + 0x7FFFu + ((x.u >> 16) & 1u);  // RNE
  return (unsigned short)(r >> 16);
}

// async global->LDS, 16B per lane
__device__ __forceinline__ void gll16(const void* g, void* l) {
  __builtin_amdgcn_global_load_lds(
      (__attribute__((address_space(1))) void*)g,
      (__attribute__((address_space(3))) void*)l, 16, 0, 0);
}

// packed f32x2 -> bf16x2 (RNE), one VALU op
__device__ __forceinline__ int cvtpk(float lo, float hi) {
  int r;
  asm("v_cvt_pk_bf16_f32 %0, %1, %2" : "=v"(r) : "v"(lo), "v"(hi));
  return r;
}
// v_permlane32_swap_b32: a[32:63] <-> b[0:31]. ONLY safe when a and b are
// provably-distinct registers (distinct asm outputs) — R3's self-swap of a
// copied value got register-coalesced into v_permlane32_swap v5,v5.
__device__ __forceinline__ void pl32swap(int& a, int& b) {
  asm volatile("v_permlane32_swap_b32 %0, %1" : "+v"(a), "+v"(b));
}

// ---------------------------------------------------------------------------
// fp32 -> bf16 convert (vectorized float4 -> 4x bf16)
// ---------------------------------------------------------------------------
__global__ void cvtbf(const float* __restrict__ in, unsigned short* __restrict__ out, const int n) {
  const int t = blockIdx.x * blockDim.x + threadIdx.x;
  const int stride = gridDim.x * blockDim.x;
  for (int i = t * 4; i < n; i += stride * 4) {
    const float4 v = *(const float4*)&in[i];
    us4v o;
    o[0] = f2bf(v.x); o[1] = f2bf(v.y); o[2] = f2bf(v.z); o[3] = f2bf(v.w);
    *(us4v*)&out[i] = o;
  }
}

// ---------------------------------------------------------------------------
// weight transpose + convert: W[k][n] fp32 -> Wt[n][k] bf16   (1024x1024, x4)
// ---------------------------------------------------------------------------
__global__ void wtrans(const float* __restrict__ W0, const float* __restrict__ W1,
                       const float* __restrict__ W2, const float* __restrict__ W3,
                       unsigned short* __restrict__ T0, unsigned short* __restrict__ T1,
                       unsigned short* __restrict__ T2, unsigned short* __restrict__ T3) {
  __shared__ float t[32][33];
  const int z = blockIdx.z;
  const float* W = (z == 0) ? W0 : (z == 1) ? W1 : (z == 2) ? W2 : W3;
  unsigned short* T = (z == 0) ? T0 : (z == 1) ? T1 : (z == 2) ? T2 : T3;
  const int n0 = blockIdx.x * 32, k0 = blockIdx.y * 32;
  const int tx = threadIdx.x, ty = threadIdx.y;  // 32 x 8
#pragma unroll
  for (int i = 0; i < 4; ++i)
    t[ty + 8 * i][tx] = W[(size_t)(k0 + ty + 8 * i) * D_MODEL + n0 + tx];
  __syncthreads();
#pragma unroll
  for (int i = 0; i < 4; ++i)
    T[(size_t)(n0 + ty + 8 * i) * D_MODEL + k0 + tx] = f2bf(t[tx][ty + 8 * i]);
}

// ---------------------------------------------------------------------------
// bf16 GEMM: C[M=8192][N=1024] = A[M][K=1024] @ Wt[N][K]^T + bias
// (unchanged from R2-verified version)
// ---------------------------------------------------------------------------
__global__ __launch_bounds__(256) void gemm128(
    const unsigned short* __restrict__ A, const unsigned short* __restrict__ Bt,
    const float* __restrict__ bias, unsigned short* __restrict__ outb,
    float* __restrict__ outf, const int mode) {
  __shared__ __align__(16) unsigned short Alds[128 * 64];
  __shared__ __align__(16) unsigned short Blds[128 * 64];
  const int tid = threadIdx.x;
  const int lane = tid & 63;
  const int w = tid >> 6;
  const int wr = w >> 1, wc = w & 1;
  const int m0 = blockIdx.y * 128, n0 = blockIdx.x * 128;
  const int srow = tid >> 3, sslot = tid & 7;

  f32x4 acc[4][4] = {};

  for (int kk = 0; kk < D_MODEL / 64; ++kk) {
    __syncthreads();
#pragma unroll
    for (int i = 0; i < 4; ++i) {
      const int r = srow + 32 * i;
      const int gc = kk * 64 + ((sslot ^ (r & 7)) << 3);
      gll16(A + (size_t)(m0 + r) * D_MODEL + gc, &Alds[tid * 8 + i * 2048]);
      gll16(Bt + (size_t)(n0 + r) * D_MODEL + gc, &Blds[tid * 8 + i * 2048]);
    }
    __syncthreads();
#pragma unroll
    for (int kf = 0; kf < 2; ++kf) {
      const int sb = kf * 4 + (lane >> 4);
      bf16x8 a[4], b[4];
#pragma unroll
      for (int m = 0; m < 4; ++m) {
        const int row = wr * 64 + m * 16 + (lane & 15);
        a[m] = *(const bf16x8*)&Alds[row * 64 + ((sb ^ (row & 7)) << 3)];
      }
#pragma unroll
      for (int n = 0; n < 4; ++n) {
        const int row = wc * 64 + n * 16 + (lane & 15);
        b[n] = *(const bf16x8*)&Blds[row * 64 + ((sb ^ (row & 7)) << 3)];
      }
#pragma unroll
      for (int m = 0; m < 4; ++m)
#pragma unroll
        for (int n = 0; n < 4; ++n)
          acc[m][n] = __builtin_amdgcn_mfma_f32_16x16x32_bf16(a[m], b[n], acc[m][n], 0, 0, 0);
    }
  }

#pragma unroll
  for (int m = 0; m < 4; ++m) {
    const int rb = m0 + wr * 64 + m * 16 + ((lane >> 4) << 2);
#pragma unroll
    for (int n = 0; n < 4; ++n) {
      const int col = n0 + wc * 64 + n * 16 + (lane & 15);
      const float bv = bias[col];
#pragma unroll
      for (int j = 0; j < 4; ++j) {
        const int row = rb + j;
        const float v = acc[m][n][j] + bv;
        if (mode == 2) {
          outf[(size_t)row * D_MODEL + col] = v;
        } else {
          const int b_ = row >> 11, s_ = row & (SEQ - 1);
          const int h_ = col >> 6, d_ = col & (DK - 1);
          size_t idx;
          if (mode == 0) idx = (((size_t)(b_ * NH + h_)) * SEQ + s_) * DK + d_;
          else           idx = (((size_t)(b_ * NH + h_)) * DK + d_) * SEQ + s_;
          outb[idx] = f2bf(v);
        }
      }
    }
  }
}

// ---------------------------------------------------------------------------
// causal flash attention: R2-verified compute body + T4 counted-vmcnt
// pipeline + unpaired heavy-first grid.
// Block = (bh, strip): 128 q-rows, 4 waves x 32 rows (lane&31 -> q-row).
// K [kv][d], Vt [d][kv] double-buffered swizzled LDS via global_load_lds.
// Schedule per phase:  waitcnt vmcnt(4) [tile t ready, tile t+1 in flight]
//   -> s_barrier -> compute(t) -> s_barrier -> stage(t+2 -> buf[t&1]).
// Stage after the post-compute barrier = race-free buffer reuse; counted
// vmcnt means loads are never drained to 0 in-loop (T4).
// ---------------------------------------------------------------------------
__global__ __launch_bounds__(256, 4) void attn4w(
    const unsigned short* __restrict__ Q, const unsigned short* __restrict__ K,
    const unsigned short* __restrict__ Vt, unsigned short* __restrict__ O) {
  __shared__ __align__(16) unsigned short Klds[2 * 64 * 64];
  __shared__ __align__(16) unsigned short Vlds[2 * 64 * 64];

  const int tid = threadIdx.x, lane = tid & 63, w = tid >> 6;
  const int lq = lane & 31, hi = lane >> 5;
  const int bh = blockIdx.x;
  const int strip = 15 - (int)blockIdx.y;  // heavy strips dispatched first
  const size_t qkbase = (size_t)bh * SEQ * DK;
  const size_t vbase = (size_t)bh * DK * SEQ;
  const int srow = tid >> 3, sslot = tid & 7;
  const int b_ = bh >> 4, h_ = bh & (NH - 1);

  const int q0 = strip * 128;
  const int qw0 = q0 + w * 32;  // wave's first q-row
  const int qg = qw0 + lq;      // this lane's q-row
  const int n = 2 * strip + 2;  // kv phases (64 each) covering q0+128 rows

  // Q as B-operand frags: col=lane&31 -> q, k = hi*8 + ks*16 + e.
  // Pre-scaled by 1/sqrt(DK)=0.125 (power of 2 -> exact in bf16).
  bf16x8 qb[4];
  {
    const unsigned short* qp = Q + qkbase + (size_t)qg * DK + hi * 8;
#pragma unroll
    for (int ks = 0; ks < 4; ++ks) {
      qb[ks] = *(const bf16x8*)(qp + ks * 16);
#pragma unroll
      for (int e = 0; e < 8; ++e)
        qb[ks][e] = (__bf16)((float)qb[ks][e] * 0.125f);
    }
  }

  float m = -3e38f, l = 0.f;
  f32x16 o0 = {}, o1 = {};

  // prologue: stage tiles 0 and 1 (n >= 2 always)
#pragma unroll
  for (int i = 0; i < 2; ++i) {
    const int r = srow + 32 * i;
    const int sc = (sslot ^ (r & 7)) << 3;
    gll16(K + qkbase + (size_t)r * DK + sc, &Klds[tid * 8 + i * 2048]);
    gll16(Vt + vbase + (size_t)r * SEQ + sc, &Vlds[tid * 8 + i * 2048]);
  }
#pragma unroll
  for (int i = 0; i < 2; ++i) {
    const int r = srow + 32 * i;
    const int sc = (sslot ^ (r & 7)) << 3;
    gll16(K + qkbase + (size_t)(64 + r) * DK + sc, &Klds[4096 + tid * 8 + i * 2048]);
    gll16(Vt + vbase + (size_t)r * SEQ + 64 + sc, &Vlds[4096 + tid * 8 + i * 2048]);
  }

  for (int jt = 0; jt < n; ++jt) {
    const int cur = jt & 1;
    // tile jt complete; tile jt+1's 4 loads may stay in flight (T4)
    if (jt + 1 < n) asm volatile("s_waitcnt vmcnt(4)" ::: "memory");
    else            asm volatile("s_waitcnt vmcnt(0)" ::: "memory");
    __builtin_amdgcn_s_barrier();
    asm volatile("" ::: "memory");

    if (64 * jt < qw0 + 32) {  // skip fully-masked phases
      const unsigned short* Kl = &Klds[cur * 4096];
      const unsigned short* Vl = &Vlds[cur * 4096];

      // S^T = K·Q^T : st0 = kv 0..31, st1 = kv 32..63 (cols = 32 q's)
      f32x16 st0 = {}, st1 = {};
      __builtin_amdgcn_s_setprio(1);
#pragma unroll
      for (int ks = 0; ks < 4; ++ks) {
        const int so = ((ks * 2 + hi) ^ (lq & 7)) << 3;
        const bf16x8 ka0 = *(const bf16x8*)&Kl[lq * 64 + so];
        const bf16x8 ka1 = *(const bf16x8*)&Kl[(32 + lq) * 64 + so];
        st0 = __builtin_amdgcn_mfma_f32_32x32x16_bf16(ka0, qb[ks], st0, 0, 0, 0);
        st1 = __builtin_amdgcn_mfma_f32_32x32x16_bf16(ka1, qb[ks], st1, 0, 0, 0);
      }
      __builtin_amdgcn_s_setprio(0);

      // causal mask: kv = 64*jt + kvb*32 + (r&3)+8*(r>>2)+4*hi  vs  q-row qg
      if (64 * jt + 63 > qw0) {
        const int rb = 64 * jt + 4 * hi - qg;
#pragma unroll
        for (int r = 0; r < 16; ++r) {
          const int crow0 = (r & 3) + 8 * (r >> 2);
          if (crow0 + rb > 0)      st0[r] = -3e38f;
          if (crow0 + 32 + rb > 0) st1[r] = -3e38f;
        }
      }

      // row max: lane-local tree + one cross-half exchange
      float tmax[8];
#pragma unroll
      for (int r = 0; r < 8; ++r)
        tmax[r] = fmaxf(fmaxf(st0[r], st0[r + 8]), fmaxf(st1[r], st1[r + 8]));
      float mx = fmaxf(fmaxf(fmaxf(tmax[0], tmax[1]), fmaxf(tmax[2], tmax[3])),
                       fmaxf(fmaxf(tmax[4], tmax[5]), fmaxf(tmax[6], tmax[7])));
      mx = fmaxf(mx, __shfl_xor(mx, 32));

      // defer-max (T13, THR=8): skip rescale when max barely grew
      if (__any((int)(mx > m + 8.0f))) {
        const float mnew = fmaxf(m, mx);
        const float alpha = exp2f((m - mnew) * 1.44269504f);
        m = mnew;
        l *= alpha;
#pragma unroll
        for (int r = 0; r < 16; ++r) { o0[r] *= alpha; o1[r] *= alpha; }
      }

      // exp (P kept in st regs, bounded by e^8 under defer)
      const float ml = m * 1.44269504f;
#pragma unroll
      for (int r = 0; r < 16; ++r) {
        st0[r] = exp2f(__builtin_fmaf(st0[r], 1.44269504f, -ml));
        st1[r] = exp2f(__builtin_fmaf(st1[r], 1.44269504f, -ml));
      }

      // row sum: tree + cross-half
      float tsum[8];
#pragma unroll
      for (int r = 0; r < 8; ++r)
        tsum[r] = (st0[r] + st0[r + 8]) + (st1[r] + st1[r + 8]);
      float rs = ((tsum[0] + tsum[1]) + (tsum[2] + tsum[3])) +
                 ((tsum[4] + tsum[5]) + (tsum[6] + tsum[7]));
      rs += __shfl_xor(rs, 32);
      l += rs;

      // P -> bf16 B-frags via cvt_pk + permlane32_swap (T12; distinct asm
      // outputs -> no aliasing hazard)
      bf16x8 pb[4];
#pragma unroll
      for (int ks = 0; ks < 4; ++ks) {
        const int base = (ks & 1) * 8;
        float p0, p1, p2, p3, p4, p5, p6, p7;
        if (ks < 2) {
          p0 = st0[base + 0]; p1 = st0[base + 1]; p2 = st0[base + 2]; p3 = st0[base + 3];
          p4 = st0[base + 4]; p5 = st0[base + 5]; p6 = st0[base + 6]; p7 = st0[base + 7];
        } else {
          p0 = st1[base + 0]; p1 = st1[base + 1]; p2 = st1[base + 2]; p3 = st1[base + 3];
          p4 = st1[base + 4]; p5 = st1[base + 5]; p6 = st1[base + 6]; p7 = st1[base + 7];
        }
        int a0 = cvtpk(p0, p1), a1 = cvtpk(p2, p3);
        int a2 = cvtpk(p4, p5), a3 = cvtpk(p6, p7);
        pl32swap(a0, a2);
        pl32swap(a1, a3);
        union { int i[4]; bf16x8 v; } u;
        u.i[0] = a0; u.i[1] = a1; u.i[2] = a2; u.i[3] = a3;
        pb[ks] = u.v;
      }

      // O^T += V^T·P^T   (A = Vt rows d from LDS, B = pb)
      __builtin_amdgcn_s_setprio(1);
#pragma unroll
      for (int ks = 0; ks < 4; ++ks) {
        const int so = ((ks * 2 + hi) ^ (lq & 7)) << 3;
        const bf16x8 va0 = *(const bf16x8*)&Vl[lq * 64 + so];
        const bf16x8 va1 = *(const bf16x8*)&Vl[(32 + lq) * 64 + so];
        o0 = __builtin_amdgcn_mfma_f32_32x32x16_bf16(va0, pb[ks], o0, 0, 0, 0);
        o1 = __builtin_amdgcn_mfma_f32_32x32x16_bf16(va1, pb[ks], o1, 0, 0, 0);
      }
      __builtin_amdgcn_s_setprio(0);
    }

    asm volatile("" ::: "memory");
    __builtin_amdgcn_s_barrier();  // all waves done reading buf[cur]

    // stage tile jt+2 into buf[cur] (just freed)
    if (jt + 2 < n) {
      const int kv0 = (jt + 2) * 64;
#pragma unroll
      for (int i = 0; i < 2; ++i) {
        const int r = srow + 32 * i;
        const int sc = (sslot ^ (r & 7)) << 3;
        gll16(K + qkbase + (size_t)(kv0 + r) * DK + sc,
              &Klds[cur * 4096 + tid * 8 + i * 2048]);
        gll16(Vt + vbase + (size_t)r * SEQ + kv0 + sc,
              &Vlds[cur * 4096 + tid * 8 + i * 2048]);
      }
    }
  }

  // epilogue: O[b*s][h*64+d]; lane owns q-row qg; o rows are d.
  const float rl = 1.0f / l;
  unsigned short* orow = O + (size_t)(b_ * SEQ + qg) * D_MODEL + h_ * DK;
#pragma unroll
  for (int g = 0; g < 4; ++g) {
    us4v pk0, pk1;
#pragma unroll
    for (int j = 0; j < 4; ++j) {
      pk0[j] = f2bf(o0[4 * g + j] * rl);
      pk1[j] = f2bf(o1[4 * g + j] * rl);
    }
    const int d0 = 8 * g + 4 * hi;
    *(us4v*)&orow[d0] = pk0;
    *(us4v*)&orow[32 + d0] = pk1;
  }
}

// ---------------------------------------------------------------------------
extern "C" void kernel_launch(void* const* d_in, const int* in_sizes, int n_in,
                              void* d_out, int out_size, void* d_ws, size_t ws_size,
                              hipStream_t stream) {
  const float* ctx = (const float*)d_in[0];
  const float* val = (const float*)d_in[1];
  // d_in[2] = mask: statically causal triu(k=1); handled analytically.
  const float* Wq = (const float*)d_in[3];
  const float* bq = (const float*)d_in[4];
  const float* Wk = (const float*)d_in[5];
  const float* bk = (const float*)d_in[6];
  const float* Wv = (const float*)d_in[7];
  const float* bv = (const float*)d_in[8];
  const float* Wo = (const float*)d_in[9];
  const float* bo = (const float*)d_in[10];

  unsigned short* ws = (unsigned short*)d_ws;
  const size_t XSZ = (size_t)BATCH * SEQ * D_MODEL;  // 8388608
  const size_t WSZ = (size_t)D_MODEL * D_MODEL;      // 1048576
  unsigned short* Xc  = ws;
  unsigned short* Xv  = Xc + XSZ;
  unsigned short* Wqt = Xv + XSZ;
  unsigned short* Wkt = Wqt + WSZ;
  unsigned short* Wvt = Wkt + WSZ;
  unsigned short* Wot = Wvt + WSZ;
  unsigned short* Qb  = Wot + WSZ;
  unsigned short* Kb  = Qb + XSZ;
  unsigned short* Vtb = Kb + XSZ;
  unsigned short* Ob  = Vtb + XSZ;

  cvtbf<<<1024, 256, 0, stream>>>(ctx, Xc, (int)XSZ);
  cvtbf<<<1024, 256, 0, stream>>>(val, Xv, (int)XSZ);
  wtrans<<<dim3(32, 32, 4), dim3(32, 8), 0, stream>>>(Wq, Wk, Wv, Wo, Wqt, Wkt, Wvt, Wot);

  dim3 gg(D_MODEL / 128, BATCH * SEQ / 128);  // (8, 64)
  gemm128<<<gg, 256, 0, stream>>>(Xc, Wqt, bq, Qb, nullptr, 0);
  gemm128<<<gg, 256, 0, stream>>>(Xc, Wkt, bk, Kb, nullptr, 0);
  gemm128<<<gg, 256, 0, stream>>>(Xv, Wvt, bv, Vtb, nullptr, 1);

  // 1024 blocks: x = bh (64, %8 -> XCD locality), y = 16 strips heavy-first
  attn4w<<<dim3(BATCH * NH, 16), 256, 0, stream>>>(Qb, Kb, Vtb, Ob);

  gemm128<<<gg, 256, 0, stream>>>(Ob, Wot, bo, nullptr, (float*)d_out, 2);
}

// Round 7
// 195.274 us; speedup vs baseline: 1.5060x; 1.1056x over previous
//
#include <hip/hip_runtime.h>
#include <stdint.h>

#define D_MODEL 1024
#define SEQ 2048
#define BATCH 4
#define NH 16
#define DK 64

typedef float f32x4 __attribute__((ext_vector_type(4)));
typedef float f32x16 __attribute__((ext_vector_type(16)));
typedef __bf16 bf16x8 __attribute__((ext_vector_type(8)));
typedef unsigned short us4v __attribute__((ext_vector_type(4)));

__device__ __forceinline__ unsigned short f2bf(float f) {
  union { float f; unsigned u; } x; x.f = f;
  unsigned r = x.u + 0x7FFFu + ((x.u >> 16) & 1u);  // RNE
  return (unsigned short)(r >> 16);
}

// async global->LDS, 16B per lane
__device__ __forceinline__ void gll16(const void* g, void* l) {
  __builtin_amdgcn_global_load_lds(
      (__attribute__((address_space(1))) void*)g,
      (__attribute__((address_space(3))) void*)l, 16, 0, 0);
}

// packed f32x2 -> bf16x2 (RNE), one VALU op
__device__ __forceinline__ int cvtpk(float lo, float hi) {
  int r;
  asm("v_cvt_pk_bf16_f32 %0, %1, %2" : "=v"(r) : "v"(lo), "v"(hi));
  return r;
}
// v_permlane32_swap_b32: a[32:63] <-> b[0:31]. ONLY safe when a and b are
// provably-distinct registers (distinct asm outputs) — R3's self-swap of a
// copied value got register-coalesced into v_permlane32_swap v5,v5.
__device__ __forceinline__ void pl32swap(int& a, int& b) {
  asm volatile("v_permlane32_swap_b32 %0, %1" : "+v"(a), "+v"(b));
}

// ---------------------------------------------------------------------------
// fp32 -> bf16 convert (vectorized float4 -> 4x bf16)
// ---------------------------------------------------------------------------
__global__ void cvtbf(const float* __restrict__ in, unsigned short* __restrict__ out, const int n) {
  const int t = blockIdx.x * blockDim.x + threadIdx.x;
  const int stride = gridDim.x * blockDim.x;
  for (int i = t * 4; i < n; i += stride * 4) {
    const float4 v = *(const float4*)&in[i];
    us4v o;
    o[0] = f2bf(v.x); o[1] = f2bf(v.y); o[2] = f2bf(v.z); o[3] = f2bf(v.w);
    *(us4v*)&out[i] = o;
  }
}

// ---------------------------------------------------------------------------
// weight transpose + convert: W[k][n] fp32 -> Wt[n][k] bf16   (1024x1024, x4)
// ---------------------------------------------------------------------------
__global__ void wtrans(const float* __restrict__ W0, const float* __restrict__ W1,
                       const float* __restrict__ W2, const float* __restrict__ W3,
                       unsigned short* __restrict__ T0, unsigned short* __restrict__ T1,
                       unsigned short* __restrict__ T2, unsigned short* __restrict__ T3) {
  __shared__ float t[32][33];
  const int z = blockIdx.z;
  const float* W = (z == 0) ? W0 : (z == 1) ? W1 : (z == 2) ? W2 : W3;
  unsigned short* T = (z == 0) ? T0 : (z == 1) ? T1 : (z == 2) ? T2 : T3;
  const int n0 = blockIdx.x * 32, k0 = blockIdx.y * 32;
  const int tx = threadIdx.x, ty = threadIdx.y;  // 32 x 8
#pragma unroll
  for (int i = 0; i < 4; ++i)
    t[ty + 8 * i][tx] = W[(size_t)(k0 + ty + 8 * i) * D_MODEL + n0 + tx];
  __syncthreads();
#pragma unroll
  for (int i = 0; i < 4; ++i)
    T[(size_t)(n0 + ty + 8 * i) * D_MODEL + k0 + tx] = f2bf(t[tx][ty + 8 * i]);
}

// ---------------------------------------------------------------------------
// bf16 GEMM: C[M=8192][N=1024] = A[M][K=1024] @ Wt[N][K]^T + bias
// 128x128 tile, BK=64, 4 waves (2x2 of 64x64), mfma_f32_16x16x32_bf16.
// R7: double-buffered LDS + T4 counted-vmcnt schedule (attn4w-proven):
//   prologue stage(t0,t1); loop: vmcnt(8) -> barrier -> compute(t) ->
//   barrier -> stage(t+2 into buf[t&1]). Loads never drained to 0 in-loop.
// + bijective XCD-chunked block swizzle (512 blocks % 8 == 0): each XCD's
//   64 blocks = 8 m-panels x 8 n-panels -> 2MB A + 2MB B resident per L2.
// mode 0: out bf16 [b,h,s,d] (Q,K); mode 1: out bf16 [b,h,d,s] (V^T);
// mode 2: out fp32 [m][n] (final projection)
// ---------------------------------------------------------------------------
__global__ __launch_bounds__(256) void gemm128(
    const unsigned short* __restrict__ A, const unsigned short* __restrict__ Bt,
    const float* __restrict__ bias, unsigned short* __restrict__ outb,
    float* __restrict__ outf, const int mode) {
  __shared__ __align__(16) unsigned short Alds[2 * 128 * 64];
  __shared__ __align__(16) unsigned short Blds[2 * 128 * 64];
  const int tid = threadIdx.x;
  const int lane = tid & 63;
  const int w = tid >> 6;
  const int wr = w >> 1, wc = w & 1;

  // XCD-chunked swizzle (grid is always 8 x 64 = 512 here; 512 % 8 == 0)
  int flat = (int)blockIdx.x + 8 * (int)blockIdx.y;
  flat = (flat & 7) * 64 + (flat >> 3);
  const int n0 = (flat & 7) * 128;
  const int m0 = (flat >> 3) * 128;

  const int srow = tid >> 3, sslot = tid & 7;

  auto stage = [&](int kk, int buf) {
#pragma unroll
    for (int i = 0; i < 4; ++i) {
      const int r = srow + 32 * i;
      const int gc = kk * 64 + ((sslot ^ (r & 7)) << 3);
      gll16(A + (size_t)(m0 + r) * D_MODEL + gc, &Alds[buf * 8192 + tid * 8 + i * 2048]);
      gll16(Bt + (size_t)(n0 + r) * D_MODEL + gc, &Blds[buf * 8192 + tid * 8 + i * 2048]);
    }
  };

  f32x4 acc[4][4] = {};

  // prologue: stage K-tiles 0 and 1 (D_MODEL/64 = 16 >= 2)
  stage(0, 0);
  stage(1, 1);

  const int NK = D_MODEL / 64;  // 16
  for (int kk = 0; kk < NK; ++kk) {
    const int cur = kk & 1;
    // tile kk's 8 loads complete; tile kk+1's 8 may stay in flight (T4)
    if (kk + 1 < NK) asm volatile("s_waitcnt vmcnt(8)" ::: "memory");
    else             asm volatile("s_waitcnt vmcnt(0)" ::: "memory");
    __builtin_amdgcn_s_barrier();
    asm volatile("" ::: "memory");

    const unsigned short* Al = &Alds[cur * 8192];
    const unsigned short* Bl = &Blds[cur * 8192];
#pragma unroll
    for (int kf = 0; kf < 2; ++kf) {
      const int sb = kf * 4 + (lane >> 4);
      bf16x8 a[4], b[4];
#pragma unroll
      for (int m = 0; m < 4; ++m) {
        const int row = wr * 64 + m * 16 + (lane & 15);
        a[m] = *(const bf16x8*)&Al[row * 64 + ((sb ^ (row & 7)) << 3)];
      }
#pragma unroll
      for (int n = 0; n < 4; ++n) {
        const int row = wc * 64 + n * 16 + (lane & 15);
        b[n] = *(const bf16x8*)&Bl[row * 64 + ((sb ^ (row & 7)) << 3)];
      }
#pragma unroll
      for (int m = 0; m < 4; ++m)
#pragma unroll
        for (int n = 0; n < 4; ++n)
          acc[m][n] = __builtin_amdgcn_mfma_f32_16x16x32_bf16(a[m], b[n], acc[m][n], 0, 0, 0);
    }

    asm volatile("" ::: "memory");
    __builtin_amdgcn_s_barrier();  // all waves done reading buf[cur]

    if (kk + 2 < NK) stage(kk + 2, cur);  // overwrite just-freed buffer
  }

#pragma unroll
  for (int m = 0; m < 4; ++m) {
    const int rb = m0 + wr * 64 + m * 16 + ((lane >> 4) << 2);
#pragma unroll
    for (int n = 0; n < 4; ++n) {
      const int col = n0 + wc * 64 + n * 16 + (lane & 15);
      const float bv = bias[col];
#pragma unroll
      for (int j = 0; j < 4; ++j) {
        const int row = rb + j;
        const float v = acc[m][n][j] + bv;
        if (mode == 2) {
          outf[(size_t)row * D_MODEL + col] = v;
        } else {
          const int b_ = row >> 11, s_ = row & (SEQ - 1);
          const int h_ = col >> 6, d_ = col & (DK - 1);
          size_t idx;
          if (mode == 0) idx = (((size_t)(b_ * NH + h_)) * SEQ + s_) * DK + d_;
          else           idx = (((size_t)(b_ * NH + h_)) * DK + d_) * SEQ + s_;
          outb[idx] = f2bf(v);
        }
      }
    }
  }
}

// ---------------------------------------------------------------------------
// causal flash attention: R6-verified kernel, unchanged.
// Block = (bh, strip): 128 q-rows, 4 waves x 32 rows (lane&31 -> q-row).
// K [kv][d], Vt [d][kv] double-buffered swizzled LDS via global_load_lds.
// vmcnt(4) counted waits; stage after post-compute barrier.
// ---------------------------------------------------------------------------
__global__ __launch_bounds__(256, 4) void attn4w(
    const unsigned short* __restrict__ Q, const unsigned short* __restrict__ K,
    const unsigned short* __restrict__ Vt, unsigned short* __restrict__ O) {
  __shared__ __align__(16) unsigned short Klds[2 * 64 * 64];
  __shared__ __align__(16) unsigned short Vlds[2 * 64 * 64];

  const int tid = threadIdx.x, lane = tid & 63, w = tid >> 6;
  const int lq = lane & 31, hi = lane >> 5;
  const int bh = blockIdx.x;
  const int strip = 15 - (int)blockIdx.y;  // heavy strips dispatched first
  const size_t qkbase = (size_t)bh * SEQ * DK;
  const size_t vbase = (size_t)bh * DK * SEQ;
  const int srow = tid >> 3, sslot = tid & 7;
  const int b_ = bh >> 4, h_ = bh & (NH - 1);

  const int q0 = strip * 128;
  const int qw0 = q0 + w * 32;  // wave's first q-row
  const int qg = qw0 + lq;      // this lane's q-row
  const int n = 2 * strip + 2;  // kv phases (64 each)

  // Q as B-operand frags: col=lane&31 -> q, k = hi*8 + ks*16 + e.
  // Pre-scaled by 1/sqrt(DK)=0.125 (power of 2 -> exact in bf16).
  bf16x8 qb[4];
  {
    const unsigned short* qp = Q + qkbase + (size_t)qg * DK + hi * 8;
#pragma unroll
    for (int ks = 0; ks < 4; ++ks) {
      qb[ks] = *(const bf16x8*)(qp + ks * 16);
#pragma unroll
      for (int e = 0; e < 8; ++e)
        qb[ks][e] = (__bf16)((float)qb[ks][e] * 0.125f);
    }
  }

  float m = -3e38f, l = 0.f;
  f32x16 o0 = {}, o1 = {};

  // prologue: stage tiles 0 and 1 (n >= 2 always)
#pragma unroll
  for (int i = 0; i < 2; ++i) {
    const int r = srow + 32 * i;
    const int sc = (sslot ^ (r & 7)) << 3;
    gll16(K + qkbase + (size_t)r * DK + sc, &Klds[tid * 8 + i * 2048]);
    gll16(Vt + vbase + (size_t)r * SEQ + sc, &Vlds[tid * 8 + i * 2048]);
  }
#pragma unroll
  for (int i = 0; i < 2; ++i) {
    const int r = srow + 32 * i;
    const int sc = (sslot ^ (r & 7)) << 3;
    gll16(K + qkbase + (size_t)(64 + r) * DK + sc, &Klds[4096 + tid * 8 + i * 2048]);
    gll16(Vt + vbase + (size_t)r * SEQ + 64 + sc, &Vlds[4096 + tid * 8 + i * 2048]);
  }

  for (int jt = 0; jt < n; ++jt) {
    const int cur = jt & 1;
    if (jt + 1 < n) asm volatile("s_waitcnt vmcnt(4)" ::: "memory");
    else            asm volatile("s_waitcnt vmcnt(0)" ::: "memory");
    __builtin_amdgcn_s_barrier();
    asm volatile("" ::: "memory");

    if (64 * jt < qw0 + 32) {  // skip fully-masked phases
      const unsigned short* Kl = &Klds[cur * 4096];
      const unsigned short* Vl = &Vlds[cur * 4096];

      // S^T = K·Q^T : st0 = kv 0..31, st1 = kv 32..63 (cols = 32 q's)
      f32x16 st0 = {}, st1 = {};
      __builtin_amdgcn_s_setprio(1);
#pragma unroll
      for (int ks = 0; ks < 4; ++ks) {
        const int so = ((ks * 2 + hi) ^ (lq & 7)) << 3;
        const bf16x8 ka0 = *(const bf16x8*)&Kl[lq * 64 + so];
        const bf16x8 ka1 = *(const bf16x8*)&Kl[(32 + lq) * 64 + so];
        st0 = __builtin_amdgcn_mfma_f32_32x32x16_bf16(ka0, qb[ks], st0, 0, 0, 0);
        st1 = __builtin_amdgcn_mfma_f32_32x32x16_bf16(ka1, qb[ks], st1, 0, 0, 0);
      }
      __builtin_amdgcn_s_setprio(0);

      // causal mask: kv = 64*jt + kvb*32 + (r&3)+8*(r>>2)+4*hi  vs  q-row qg
      if (64 * jt + 63 > qw0) {
        const int rb = 64 * jt + 4 * hi - qg;
#pragma unroll
        for (int r = 0; r < 16; ++r) {
          const int crow0 = (r & 3) + 8 * (r >> 2);
          if (crow0 + rb > 0)      st0[r] = -3e38f;
          if (crow0 + 32 + rb > 0) st1[r] = -3e38f;
        }
      }

      // row max: lane-local tree + one cross-half exchange
      float tmax[8];
#pragma unroll
      for (int r = 0; r < 8; ++r)
        tmax[r] = fmaxf(fmaxf(st0[r], st0[r + 8]), fmaxf(st1[r], st1[r + 8]));
      float mx = fmaxf(fmaxf(fmaxf(tmax[0], tmax[1]), fmaxf(tmax[2], tmax[3])),
                       fmaxf(fmaxf(tmax[4], tmax[5]), fmaxf(tmax[6], tmax[7])));
      mx = fmaxf(mx, __shfl_xor(mx, 32));

      // defer-max (T13, THR=8): skip rescale when max barely grew
      if (__any((int)(mx > m + 8.0f))) {
        const float mnew = fmaxf(m, mx);
        const float alpha = exp2f((m - mnew) * 1.44269504f);
        m = mnew;
        l *= alpha;
#pragma unroll
        for (int r = 0; r < 16; ++r) { o0[r] *= alpha; o1[r] *= alpha; }
      }

      // exp (P kept in st regs, bounded by e^8 under defer)
      const float ml = m * 1.44269504f;
#pragma unroll
      for (int r = 0; r < 16; ++r) {
        st0[r] = exp2f(__builtin_fmaf(st0[r], 1.44269504f, -ml));
        st1[r] = exp2f(__builtin_fmaf(st1[r], 1.44269504f, -ml));
      }

      // row sum: tree + cross-half
      float tsum[8];
#pragma unroll
      for (int r = 0; r < 8; ++r)
        tsum[r] = (st0[r] + st0[r + 8]) + (st1[r] + st1[r + 8]);
      float rs = ((tsum[0] + tsum[1]) + (tsum[2] + tsum[3])) +
                 ((tsum[4] + tsum[5]) + (tsum[6] + tsum[7]));
      rs += __shfl_xor(rs, 32);
      l += rs;

      // P -> bf16 B-frags via cvt_pk + permlane32_swap (T12; distinct asm
      // outputs -> no aliasing hazard)
      bf16x8 pb[4];
#pragma unroll
      for (int ks = 0; ks < 4; ++ks) {
        const int base = (ks & 1) * 8;
        float p0, p1, p2, p3, p4, p5, p6, p7;
        if (ks < 2) {
          p0 = st0[base + 0]; p1 = st0[base + 1]; p2 = st0[base + 2]; p3 = st0[base + 3];
          p4 = st0[base + 4]; p5 = st0[base + 5]; p6 = st0[base + 6]; p7 = st0[base + 7];
        } else {
          p0 = st1[base + 0]; p1 = st1[base + 1]; p2 = st1[base + 2]; p3 = st1[base + 3];
          p4 = st1[base + 4]; p5 = st1[base + 5]; p6 = st1[base + 6]; p7 = st1[base + 7];
        }
        int a0 = cvtpk(p0, p1), a1 = cvtpk(p2, p3);
        int a2 = cvtpk(p4, p5), a3 = cvtpk(p6, p7);
        pl32swap(a0, a2);
        pl32swap(a1, a3);
        union { int i[4]; bf16x8 v; } u;
        u.i[0] = a0; u.i[1] = a1; u.i[2] = a2; u.i[3] = a3;
        pb[ks] = u.v;
      }

      // O^T += V^T·P^T   (A = Vt rows d from LDS, B = pb)
      __builtin_amdgcn_s_setprio(1);
#pragma unroll
      for (int ks = 0; ks < 4; ++ks) {
        const int so = ((ks * 2 + hi) ^ (lq & 7)) << 3;
        const bf16x8 va0 = *(const bf16x8*)&Vl[lq * 64 + so];
        const bf16x8 va1 = *(const bf16x8*)&Vl[(32 + lq) * 64 + so];
        o0 = __builtin_amdgcn_mfma_f32_32x32x16_bf16(va0, pb[ks], o0, 0, 0, 0);
        o1 = __builtin_amdgcn_mfma_f32_32x32x16_bf16(va1, pb[ks], o1, 0, 0, 0);
      }
      __builtin_amdgcn_s_setprio(0);
    }

    asm volatile("" ::: "memory");
    __builtin_amdgcn_s_barrier();  // all waves done reading buf[cur]

    // stage tile jt+2 into buf[cur] (just freed)
    if (jt + 2 < n) {
      const int kv0 = (jt + 2) * 64;
#pragma unroll
      for (int i = 0; i < 2; ++i) {
        const int r = srow + 32 * i;
        const int sc = (sslot ^ (r & 7)) << 3;
        gll16(K + qkbase + (size_t)(kv0 + r) * DK + sc,
              &Klds[cur * 4096 + tid * 8 + i * 2048]);
        gll16(Vt + vbase + (size_t)r * SEQ + kv0 + sc,
              &Vlds[cur * 4096 + tid * 8 + i * 2048]);
      }
    }
  }

  // epilogue: O[b*s][h*64+d]; lane owns q-row qg; o rows are d.
  const float rl = 1.0f / l;
  unsigned short* orow = O + (size_t)(b_ * SEQ + qg) * D_MODEL + h_ * DK;
#pragma unroll
  for (int g = 0; g < 4; ++g) {
    us4v pk0, pk1;
#pragma unroll
    for (int j = 0; j < 4; ++j) {
      pk0[j] = f2bf(o0[4 * g + j] * rl);
      pk1[j] = f2bf(o1[4 * g + j] * rl);
    }
    const int d0 = 8 * g + 4 * hi;
    *(us4v*)&orow[d0] = pk0;
    *(us4v*)&orow[32 + d0] = pk1;
  }
}

// ---------------------------------------------------------------------------
extern "C" void kernel_launch(void* const* d_in, const int* in_sizes, int n_in,
                              void* d_out, int out_size, void* d_ws, size_t ws_size,
                              hipStream_t stream) {
  const float* ctx = (const float*)d_in[0];
  const float* val = (const float*)d_in[1];
  // d_in[2] = mask: statically causal triu(k=1); handled analytically.
  const float* Wq = (const float*)d_in[3];
  const float* bq = (const float*)d_in[4];
  const float* Wk = (const float*)d_in[5];
  const float* bk = (const float*)d_in[6];
  const float* Wv = (const float*)d_in[7];
  const float* bv = (const float*)d_in[8];
  const float* Wo = (const float*)d_in[9];
  const float* bo = (const float*)d_in[10];

  unsigned short* ws = (unsigned short*)d_ws;
  const size_t XSZ = (size_t)BATCH * SEQ * D_MODEL;  // 8388608
  const size_t WSZ = (size_t)D_MODEL * D_MODEL;      // 1048576
  unsigned short* Xc  = ws;
  unsigned short* Xv  = Xc + XSZ;
  unsigned short* Wqt = Xv + XSZ;
  unsigned short* Wkt = Wqt + WSZ;
  unsigned short* Wvt = Wkt + WSZ;
  unsigned short* Wot = Wvt + WSZ;
  unsigned short* Qb  = Wot + WSZ;
  unsigned short* Kb  = Qb + XSZ;
  unsigned short* Vtb = Kb + XSZ;
  unsigned short* Ob  = Vtb + XSZ;

  cvtbf<<<1024, 256, 0, stream>>>(ctx, Xc, (int)XSZ);
  cvtbf<<<1024, 256, 0, stream>>>(val, Xv, (int)XSZ);
  wtrans<<<dim3(32, 32, 4), dim3(32, 8), 0, stream>>>(Wq, Wk, Wv, Wo, Wqt, Wkt, Wvt, Wot);

  dim3 gg(D_MODEL / 128, BATCH * SEQ / 128);  // (8, 64) = 512 blocks
  gemm128<<<gg, 256, 0, stream>>>(Xc, Wqt, bq, Qb, nullptr, 0);
  gemm128<<<gg, 256, 0, stream>>>(Xc, Wkt, bk, Kb, nullptr, 0);
  gemm128<<<gg, 256, 0, stream>>>(Xv, Wvt, bv, Vtb, nullptr, 1);

  // 1024 blocks: x = bh (64, %8 -> XCD locality), y = 16 strips heavy-first
  attn4w<<<dim3(BATCH * NH, 16), 256, 0, stream>>>(Qb, Kb, Vtb, Ob);

  gemm128<<<gg, 256, 0, stream>>>(Ob, Wot, bo, nullptr, (float*)d_out, 2);
}

// Round 8
// 188.330 us; speedup vs baseline: 1.5615x; 1.0369x over previous
//
#include <hip/hip_runtime.h>
#include <stdint.h>

#define D_MODEL 1024
#define SEQ 2048
#define BATCH 4
#define NH 16
#define DK 64

typedef float f32x4 __attribute__((ext_vector_type(4)));
typedef float f32x16 __attribute__((ext_vector_type(16)));
typedef __bf16 bf16x8 __attribute__((ext_vector_type(8)));
typedef unsigned short us4v __attribute__((ext_vector_type(4)));

__device__ __forceinline__ unsigned short f2bf(float f) {
  union { float f; unsigned u; } x; x.f = f;
  unsigned r = x.u + 0x7FFFu + ((x.u >> 16) & 1u);  // RNE
  return (unsigned short)(r >> 16);
}

// async global->LDS, 16B per lane
__device__ __forceinline__ void gll16(const void* g, void* l) {
  __builtin_amdgcn_global_load_lds(
      (__attribute__((address_space(1))) void*)g,
      (__attribute__((address_space(3))) void*)l, 16, 0, 0);
}

// packed f32x2 -> bf16x2 (RNE), one VALU op
__device__ __forceinline__ int cvtpk(float lo, float hi) {
  int r;
  asm("v_cvt_pk_bf16_f32 %0, %1, %2" : "=v"(r) : "v"(lo), "v"(hi));
  return r;
}
// v_permlane32_swap_b32: a[32:63] <-> b[0:31]. ONLY safe when a and b are
// provably-distinct registers (distinct asm outputs) — R3's self-swap of a
// copied value got register-coalesced into v_permlane32_swap v5,v5.
__device__ __forceinline__ void pl32swap(int& a, int& b) {
  asm volatile("v_permlane32_swap_b32 %0, %1" : "+v"(a), "+v"(b));
}
// single-instruction 2^x (vs OCML exp2f's multi-op sequence). gfx9-lineage
// scoreboards transcendental results; denormal flush-to-zero is fine here
// (P values <= 1, tiny P contribute nothing).
__device__ __forceinline__ float exp2fast(float x) {
  float r;
  asm("v_exp_f32 %0, %1" : "=v"(r) : "v"(x));
  return r;
}

// ---------------------------------------------------------------------------
// fp32 -> bf16 convert, two segments in one launch (Xc,Xv are adjacent)
// ---------------------------------------------------------------------------
__global__ void cvtbf2(const float* __restrict__ a, const float* __restrict__ b,
                       unsigned short* __restrict__ out, const int nseg) {
  const int t = blockIdx.x * blockDim.x + threadIdx.x;
  const int stride = gridDim.x * blockDim.x;
  for (int i = t * 4; i < 2 * nseg; i += stride * 4) {
    const float* src = (i < nseg) ? &a[i] : &b[i - nseg];
    const float4 v = *(const float4*)src;
    us4v o;
    o[0] = f2bf(v.x); o[1] = f2bf(v.y); o[2] = f2bf(v.z); o[3] = f2bf(v.w);
    *(us4v*)&out[i] = o;
  }
}

// ---------------------------------------------------------------------------
// weight transpose + convert: W[k][n] fp32 -> Wt[n][k] bf16   (1024x1024, x4)
// ---------------------------------------------------------------------------
__global__ void wtrans(const float* __restrict__ W0, const float* __restrict__ W1,
                       const float* __restrict__ W2, const float* __restrict__ W3,
                       unsigned short* __restrict__ T0, unsigned short* __restrict__ T1,
                       unsigned short* __restrict__ T2, unsigned short* __restrict__ T3) {
  __shared__ float t[32][33];
  const int z = blockIdx.z;
  const float* W = (z == 0) ? W0 : (z == 1) ? W1 : (z == 2) ? W2 : W3;
  unsigned short* T = (z == 0) ? T0 : (z == 1) ? T1 : (z == 2) ? T2 : T3;
  const int n0 = blockIdx.x * 32, k0 = blockIdx.y * 32;
  const int tx = threadIdx.x, ty = threadIdx.y;  // 32 x 8
#pragma unroll
  for (int i = 0; i < 4; ++i)
    t[ty + 8 * i][tx] = W[(size_t)(k0 + ty + 8 * i) * D_MODEL + n0 + tx];
  __syncthreads();
#pragma unroll
  for (int i = 0; i < 4; ++i)
    T[(size_t)(n0 + ty + 8 * i) * D_MODEL + k0 + tx] = f2bf(t[tx][ty + 8 * i]);
}

// ---------------------------------------------------------------------------
// bf16 GEMM: C[M=8192][N] = A[M][K=1024] @ Wt[N][K]^T + bias
// 128x128 tile, BK=64, 4 waves, dbuf LDS + T4 counted-vmcnt (R7-verified) +
// bijective XCD-chunked swizzle (any grid with nwg%8==0, gridDim.x pow2).
// mode 0: fused QK — N=2048; col<1024 -> outb (Q), else outb2 (K), both
//         bf16 [b,h,s,d]; bias selected likewise.
// mode 1: out bf16 [b,h,d,s] (V^T);  mode 2: out fp32 [m][n] (final proj)
// ---------------------------------------------------------------------------
__global__ __launch_bounds__(256) void gemm128(
    const unsigned short* __restrict__ A, const unsigned short* __restrict__ Bt,
    const float* __restrict__ bias, const float* __restrict__ bias2,
    unsigned short* __restrict__ outb, unsigned short* __restrict__ outb2,
    float* __restrict__ outf, const int mode) {
  __shared__ __align__(16) unsigned short Alds[2 * 128 * 64];
  __shared__ __align__(16) unsigned short Blds[2 * 128 * 64];
  const int tid = threadIdx.x;
  const int lane = tid & 63;
  const int w = tid >> 6;
  const int wr = w >> 1, wc = w & 1;

  // bijective XCD-chunked swizzle: nwg%8==0, gridDim.x = NB_N (pow2)
  const int nbn = (int)gridDim.x;
  const int chunk = (nbn * (int)gridDim.y) >> 3;
  const int nbs = __builtin_ctz(nbn);
  int flat = (int)blockIdx.x + nbn * (int)blockIdx.y;
  flat = (flat & 7) * chunk + (flat >> 3);
  const int n0 = (flat & (nbn - 1)) * 128;
  const int m0 = (flat >> nbs) * 128;

  const int srow = tid >> 3, sslot = tid & 7;

  auto stage = [&](int kk, int buf) {
#pragma unroll
    for (int i = 0; i < 4; ++i) {
      const int r = srow + 32 * i;
      const int gc = kk * 64 + ((sslot ^ (r & 7)) << 3);
      gll16(A + (size_t)(m0 + r) * D_MODEL + gc, &Alds[buf * 8192 + tid * 8 + i * 2048]);
      gll16(Bt + (size_t)(n0 + r) * D_MODEL + gc, &Blds[buf * 8192 + tid * 8 + i * 2048]);
    }
  };

  f32x4 acc[4][4] = {};

  // prologue: stage K-tiles 0 and 1
  stage(0, 0);
  stage(1, 1);

  const int NK = D_MODEL / 64;  // 16
  for (int kk = 0; kk < NK; ++kk) {
    const int cur = kk & 1;
    // tile kk's 8 loads complete; tile kk+1's 8 may stay in flight (T4)
    if (kk + 1 < NK) asm volatile("s_waitcnt vmcnt(8)" ::: "memory");
    else             asm volatile("s_waitcnt vmcnt(0)" ::: "memory");
    __builtin_amdgcn_s_barrier();
    asm volatile("" ::: "memory");

    const unsigned short* Al = &Alds[cur * 8192];
    const unsigned short* Bl = &Blds[cur * 8192];
#pragma unroll
    for (int kf = 0; kf < 2; ++kf) {
      const int sb = kf * 4 + (lane >> 4);
      bf16x8 a[4], b[4];
#pragma unroll
      for (int m = 0; m < 4; ++m) {
        const int row = wr * 64 + m * 16 + (lane & 15);
        a[m] = *(const bf16x8*)&Al[row * 64 + ((sb ^ (row & 7)) << 3)];
      }
#pragma unroll
      for (int n = 0; n < 4; ++n) {
        const int row = wc * 64 + n * 16 + (lane & 15);
        b[n] = *(const bf16x8*)&Bl[row * 64 + ((sb ^ (row & 7)) << 3)];
      }
#pragma unroll
      for (int m = 0; m < 4; ++m)
#pragma unroll
        for (int n = 0; n < 4; ++n)
          acc[m][n] = __builtin_amdgcn_mfma_f32_16x16x32_bf16(a[m], b[n], acc[m][n], 0, 0, 0);
    }

    asm volatile("" ::: "memory");
    __builtin_amdgcn_s_barrier();  // all waves done reading buf[cur]

    if (kk + 2 < NK) stage(kk + 2, cur);  // overwrite just-freed buffer
  }

#pragma unroll
  for (int m = 0; m < 4; ++m) {
    const int rb = m0 + wr * 64 + m * 16 + ((lane >> 4) << 2);
#pragma unroll
    for (int n = 0; n < 4; ++n) {
      const int col = n0 + wc * 64 + n * 16 + (lane & 15);
      const int colw = col & (D_MODEL - 1);
      const float bv = (mode == 0)
                           ? ((col < D_MODEL) ? bias[colw] : bias2[colw])
                           : bias[col];
#pragma unroll
      for (int j = 0; j < 4; ++j) {
        const int row = rb + j;
        const float v = acc[m][n][j] + bv;
        if (mode == 2) {
          outf[(size_t)row * D_MODEL + col] = v;
        } else {
          const int b_ = row >> 11, s_ = row & (SEQ - 1);
          const int h_ = colw >> 6, d_ = colw & (DK - 1);
          size_t idx;
          unsigned short* dst;
          if (mode == 0) {
            idx = (((size_t)(b_ * NH + h_)) * SEQ + s_) * DK + d_;
            dst = (col < D_MODEL) ? outb : outb2;
          } else {
            idx = (((size_t)(b_ * NH + h_)) * DK + d_) * SEQ + s_;
            dst = outb;
          }
          dst[idx] = f2bf(v);
        }
      }
    }
  }
}

// ---------------------------------------------------------------------------
// causal flash attention: R6-verified structure; R8: scores kept in log2
// domain (ln2^-1 folded into Q pre-scale) + single-instruction v_exp_f32.
// Block = (bh, strip): 128 q-rows, 4 waves x 32 rows (lane&31 -> q-row).
// K [kv][d], Vt [d][kv] double-buffered swizzled LDS via global_load_lds.
// vmcnt(4) counted waits; stage after post-compute barrier.
// ---------------------------------------------------------------------------
__global__ __launch_bounds__(256, 4) void attn4w(
    const unsigned short* __restrict__ Q, const unsigned short* __restrict__ K,
    const unsigned short* __restrict__ Vt, unsigned short* __restrict__ O) {
  __shared__ __align__(16) unsigned short Klds[2 * 64 * 64];
  __shared__ __align__(16) unsigned short Vlds[2 * 64 * 64];

  const int tid = threadIdx.x, lane = tid & 63, w = tid >> 6;
  const int lq = lane & 31, hi = lane >> 5;
  const int bh = blockIdx.x;
  const int strip = 15 - (int)blockIdx.y;  // heavy strips dispatched first
  const size_t qkbase = (size_t)bh * SEQ * DK;
  const size_t vbase = (size_t)bh * DK * SEQ;
  const int srow = tid >> 3, sslot = tid & 7;
  const int b_ = bh >> 4, h_ = bh & (NH - 1);

  const int q0 = strip * 128;
  const int qw0 = q0 + w * 32;  // wave's first q-row
  const int qg = qw0 + lq;      // this lane's q-row
  const int n = 2 * strip + 2;  // kv phases (64 each)

  // Q as B-operand frags: col=lane&31 -> q, k = hi*8 + ks*16 + e.
  // Pre-scaled by log2(e)/sqrt(DK): QK^T lands directly in log2 domain.
  bf16x8 qb[4];
  {
    const float QSCALE = 0.125f * 1.44269504f;
    const unsigned short* qp = Q + qkbase + (size_t)qg * DK + hi * 8;
#pragma unroll
    for (int ks = 0; ks < 4; ++ks) {
      qb[ks] = *(const bf16x8*)(qp + ks * 16);
#pragma unroll
      for (int e = 0; e < 8; ++e)
        qb[ks][e] = (__bf16)((float)qb[ks][e] * QSCALE);
    }
  }

  float m = -3e38f, l = 0.f;
  f32x16 o0 = {}, o1 = {};

  // prologue: stage tiles 0 and 1 (n >= 2 always)
#pragma unroll
  for (int i = 0; i < 2; ++i) {
    const int r = srow + 32 * i;
    const int sc = (sslot ^ (r & 7)) << 3;
    gll16(K + qkbase + (size_t)r * DK + sc, &Klds[tid * 8 + i * 2048]);
    gll16(Vt + vbase + (size_t)r * SEQ + sc, &Vlds[tid * 8 + i * 2048]);
  }
#pragma unroll
  for (int i = 0; i < 2; ++i) {
    const int r = srow + 32 * i;
    const int sc = (sslot ^ (r & 7)) << 3;
    gll16(K + qkbase + (size_t)(64 + r) * DK + sc, &Klds[4096 + tid * 8 + i * 2048]);
    gll16(Vt + vbase + (size_t)r * SEQ + 64 + sc, &Vlds[4096 + tid * 8 + i * 2048]);
  }

  for (int jt = 0; jt < n; ++jt) {
    const int cur = jt & 1;
    if (jt + 1 < n) asm volatile("s_waitcnt vmcnt(4)" ::: "memory");
    else            asm volatile("s_waitcnt vmcnt(0)" ::: "memory");
    __builtin_amdgcn_s_barrier();
    asm volatile("" ::: "memory");

    if (64 * jt < qw0 + 32) {  // skip fully-masked phases
      const unsigned short* Kl = &Klds[cur * 4096];
      const unsigned short* Vl = &Vlds[cur * 4096];

      // S^T (log2 domain) = K·Q^T : st0 = kv 0..31, st1 = kv 32..63
      f32x16 st0 = {}, st1 = {};
      __builtin_amdgcn_s_setprio(1);
#pragma unroll
      for (int ks = 0; ks < 4; ++ks) {
        const int so = ((ks * 2 + hi) ^ (lq & 7)) << 3;
        const bf16x8 ka0 = *(const bf16x8*)&Kl[lq * 64 + so];
        const bf16x8 ka1 = *(const bf16x8*)&Kl[(32 + lq) * 64 + so];
        st0 = __builtin_amdgcn_mfma_f32_32x32x16_bf16(ka0, qb[ks], st0, 0, 0, 0);
        st1 = __builtin_amdgcn_mfma_f32_32x32x16_bf16(ka1, qb[ks], st1, 0, 0, 0);
      }
      __builtin_amdgcn_s_setprio(0);

      // causal mask: kv = 64*jt + kvb*32 + (r&3)+8*(r>>2)+4*hi  vs  q-row qg
      if (64 * jt + 63 > qw0) {
        const int rb = 64 * jt + 4 * hi - qg;
#pragma unroll
        for (int r = 0; r < 16; ++r) {
          const int crow0 = (r & 3) + 8 * (r >> 2);
          if (crow0 + rb > 0)      st0[r] = -3e38f;
          if (crow0 + 32 + rb > 0) st1[r] = -3e38f;
        }
      }

      // row max: lane-local tree + one cross-half exchange
      float tmax[8];
#pragma unroll
      for (int r = 0; r < 8; ++r)
        tmax[r] = fmaxf(fmaxf(st0[r], st0[r + 8]), fmaxf(st1[r], st1[r + 8]));
      float mx = fmaxf(fmaxf(fmaxf(tmax[0], tmax[1]), fmaxf(tmax[2], tmax[3])),
                       fmaxf(fmaxf(tmax[4], tmax[5]), fmaxf(tmax[6], tmax[7])));
      mx = fmaxf(mx, __shfl_xor(mx, 32));

      // defer-max (T13): threshold 8*log2e in log2 domain
      if (__any((int)(mx > m + 11.5416f))) {
        const float mnew = fmaxf(m, mx);
        const float alpha = exp2fast(m - mnew);
        m = mnew;
        l *= alpha;
#pragma unroll
        for (int r = 0; r < 16; ++r) { o0[r] *= alpha; o1[r] *= alpha; }
      }

      // P = 2^(S - m): one sub + one v_exp per element
#pragma unroll
      for (int r = 0; r < 16; ++r) {
        st0[r] = exp2fast(st0[r] - m);
        st1[r] = exp2fast(st1[r] - m);
      }

      // row sum: tree + cross-half
      float tsum[8];
#pragma unroll
      for (int r = 0; r < 8; ++r)
        tsum[r] = (st0[r] + st0[r + 8]) + (st1[r] + st1[r + 8]);
      float rs = ((tsum[0] + tsum[1]) + (tsum[2] + tsum[3])) +
                 ((tsum[4] + tsum[5]) + (tsum[6] + tsum[7]));
      rs += __shfl_xor(rs, 32);
      l += rs;

      // P -> bf16 B-frags via cvt_pk + permlane32_swap (T12; distinct asm
      // outputs -> no aliasing hazard)
      bf16x8 pb[4];
#pragma unroll
      for (int ks = 0; ks < 4; ++ks) {
        const int base = (ks & 1) * 8;
        float p0, p1, p2, p3, p4, p5, p6, p7;
        if (ks < 2) {
          p0 = st0[base + 0]; p1 = st0[base + 1]; p2 = st0[base + 2]; p3 = st0[base + 3];
          p4 = st0[base + 4]; p5 = st0[base + 5]; p6 = st0[base + 6]; p7 = st0[base + 7];
        } else {
          p0 = st1[base + 0]; p1 = st1[base + 1]; p2 = st1[base + 2]; p3 = st1[base + 3];
          p4 = st1[base + 4]; p5 = st1[base + 5]; p6 = st1[base + 6]; p7 = st1[base + 7];
        }
        int a0 = cvtpk(p0, p1), a1 = cvtpk(p2, p3);
        int a2 = cvtpk(p4, p5), a3 = cvtpk(p6, p7);
        pl32swap(a0, a2);
        pl32swap(a1, a3);
        union { int i[4]; bf16x8 v; } u;
        u.i[0] = a0; u.i[1] = a1; u.i[2] = a2; u.i[3] = a3;
        pb[ks] = u.v;
      }

      // O^T += V^T·P^T   (A = Vt rows d from LDS, B = pb)
      __builtin_amdgcn_s_setprio(1);
#pragma unroll
      for (int ks = 0; ks < 4; ++ks) {
        const int so = ((ks * 2 + hi) ^ (lq & 7)) << 3;
        const bf16x8 va0 = *(const bf16x8*)&Vl[lq * 64 + so];
        const bf16x8 va1 = *(const bf16x8*)&Vl[(32 + lq) * 64 + so];
        o0 = __builtin_amdgcn_mfma_f32_32x32x16_bf16(va0, pb[ks], o0, 0, 0, 0);
        o1 = __builtin_amdgcn_mfma_f32_32x32x16_bf16(va1, pb[ks], o1, 0, 0, 0);
      }
      __builtin_amdgcn_s_setprio(0);
    }

    asm volatile("" ::: "memory");
    __builtin_amdgcn_s_barrier();  // all waves done reading buf[cur]

    // stage tile jt+2 into buf[cur] (just freed)
    if (jt + 2 < n) {
      const int kv0 = (jt + 2) * 64;
#pragma unroll
      for (int i = 0; i < 2; ++i) {
        const int r = srow + 32 * i;
        const int sc = (sslot ^ (r & 7)) << 3;
        gll16(K + qkbase + (size_t)(kv0 + r) * DK + sc,
              &Klds[cur * 4096 + tid * 8 + i * 2048]);
        gll16(Vt + vbase + (size_t)r * SEQ + kv0 + sc,
              &Vlds[cur * 4096 + tid * 8 + i * 2048]);
      }
    }
  }

  // epilogue: O[b*s][h*64+d]; lane owns q-row qg; o rows are d.
  const float rl = 1.0f / l;
  unsigned short* orow = O + (size_t)(b_ * SEQ + qg) * D_MODEL + h_ * DK;
#pragma unroll
  for (int g = 0; g < 4; ++g) {
    us4v pk0, pk1;
#pragma unroll
    for (int j = 0; j < 4; ++j) {
      pk0[j] = f2bf(o0[4 * g + j] * rl);
      pk1[j] = f2bf(o1[4 * g + j] * rl);
    }
    const int d0 = 8 * g + 4 * hi;
    *(us4v*)&orow[d0] = pk0;
    *(us4v*)&orow[32 + d0] = pk1;
  }
}

// ---------------------------------------------------------------------------
extern "C" void kernel_launch(void* const* d_in, const int* in_sizes, int n_in,
                              void* d_out, int out_size, void* d_ws, size_t ws_size,
                              hipStream_t stream) {
  const float* ctx = (const float*)d_in[0];
  const float* val = (const float*)d_in[1];
  // d_in[2] = mask: statically causal triu(k=1); handled analytically.
  const float* Wq = (const float*)d_in[3];
  const float* bq = (const float*)d_in[4];
  const float* Wk = (const float*)d_in[5];
  const float* bk = (const float*)d_in[6];
  const float* Wv = (const float*)d_in[7];
  const float* bv = (const float*)d_in[8];
  const float* Wo = (const float*)d_in[9];
  const float* bo = (const float*)d_in[10];

  unsigned short* ws = (unsigned short*)d_ws;
  const size_t XSZ = (size_t)BATCH * SEQ * D_MODEL;  // 8388608
  const size_t WSZ = (size_t)D_MODEL * D_MODEL;      // 1048576
  unsigned short* Xc  = ws;                // Xc,Xv adjacent (cvtbf2 target)
  unsigned short* Xv  = Xc + XSZ;
  unsigned short* Wqt = Xv + XSZ;          // Wqt,Wkt adjacent (fused QK B-matrix)
  unsigned short* Wkt = Wqt + WSZ;
  unsigned short* Wvt = Wkt + WSZ;
  unsigned short* Wot = Wvt + WSZ;
  unsigned short* Qb  = Wot + WSZ;
  unsigned short* Kb  = Qb + XSZ;
  unsigned short* Vtb = Kb + XSZ;
  unsigned short* Ob  = Vtb + XSZ;

  cvtbf2<<<2048, 256, 0, stream>>>(ctx, val, Xc, (int)XSZ);
  wtrans<<<dim3(32, 32, 4), dim3(32, 8), 0, stream>>>(Wq, Wk, Wv, Wo, Wqt, Wkt, Wvt, Wot);

  // fused Q+K: B = [Wqt;Wkt] (2048 rows), N=2048 -> grid (16,64)
  gemm128<<<dim3(16, 64), 256, 0, stream>>>(Xc, Wqt, bq, bk, Qb, Kb, nullptr, 0);
  // V^T: grid (8,64)
  gemm128<<<dim3(8, 64), 256, 0, stream>>>(Xv, Wvt, bv, nullptr, Vtb, nullptr, nullptr, 1);

  // 1024 blocks: x = bh (64, %8 -> XCD locality), y = 16 strips heavy-first
  attn4w<<<dim3(BATCH * NH, 16), 256, 0, stream>>>(Qb, Kb, Vtb, Ob);

  gemm128<<<dim3(8, 64), 256, 0, stream>>>(Ob, Wot, bo, nullptr, nullptr, nullptr, (float*)d_out, 2);
}

// Round 9
// 180.095 us; speedup vs baseline: 1.6329x; 1.0457x over previous
//
#include <hip/hip_runtime.h>
#include <stdint.h>

#define D_MODEL 1024
#define SEQ 2048
#define BATCH 4
#define NH 16
#define DK 64

typedef float f32x4 __attribute__((ext_vector_type(4)));
typedef float f32x16 __attribute__((ext_vector_type(16)));
typedef __bf16 bf16x8 __attribute__((ext_vector_type(8)));
typedef unsigned short us4v __attribute__((ext_vector_type(4)));

__device__ __forceinline__ unsigned short f2bf(float f) {
  union { float f; unsigned u; } x; x.f = f;
  unsigned r = x.u + 0x7FFFu + ((x.u >> 16) & 1u);  // RNE
  return (unsigned short)(r >> 16);
}

// async global->LDS, 16B per lane
__device__ __forceinline__ void gll16(const void* g, void* l) {
  __builtin_amdgcn_global_load_lds(
      (__attribute__((address_space(1))) void*)g,
      (__attribute__((address_space(3))) void*)l, 16, 0, 0);
}

// packed f32x2 -> bf16x2 (RNE), one VALU op
__device__ __forceinline__ int cvtpk(float lo, float hi) {
  int r;
  asm("v_cvt_pk_bf16_f32 %0, %1, %2" : "=v"(r) : "v"(lo), "v"(hi));
  return r;
}
// v_permlane32_swap_b32: a[32:63] <-> b[0:31]. ONLY safe when a and b are
// provably-distinct registers (distinct asm outputs) — R3's self-swap of a
// copied value got register-coalesced into v_permlane32_swap v5,v5.
__device__ __forceinline__ void pl32swap(int& a, int& b) {
  asm volatile("v_permlane32_swap_b32 %0, %1" : "+v"(a), "+v"(b));
}
// single-instruction 2^x (vs OCML exp2f's multi-op sequence)
__device__ __forceinline__ float exp2fast(float x) {
  float r;
  asm("v_exp_f32 %0, %1" : "=v"(r) : "v"(x));
  return r;
}

// ---------------------------------------------------------------------------
// fp32 -> bf16 convert, two segments in one launch (Xc,Xv are adjacent)
// ---------------------------------------------------------------------------
__global__ void cvtbf2(const float* __restrict__ a, const float* __restrict__ b,
                       unsigned short* __restrict__ out, const int nseg) {
  const int t = blockIdx.x * blockDim.x + threadIdx.x;
  const int stride = gridDim.x * blockDim.x;
  for (int i = t * 4; i < 2 * nseg; i += stride * 4) {
    const float* src = (i < nseg) ? &a[i] : &b[i - nseg];
    const float4 v = *(const float4*)src;
    us4v o;
    o[0] = f2bf(v.x); o[1] = f2bf(v.y); o[2] = f2bf(v.z); o[3] = f2bf(v.w);
    *(us4v*)&out[i] = o;
  }
}

// ---------------------------------------------------------------------------
// weight transpose + convert: W[k][n] fp32 -> Wt[n][k] bf16   (1024x1024, x4)
// ---------------------------------------------------------------------------
__global__ void wtrans(const float* __restrict__ W0, const float* __restrict__ W1,
                       const float* __restrict__ W2, const float* __restrict__ W3,
                       unsigned short* __restrict__ T0, unsigned short* __restrict__ T1,
                       unsigned short* __restrict__ T2, unsigned short* __restrict__ T3) {
  __shared__ float t[32][33];
  const int z = blockIdx.z;
  const float* W = (z == 0) ? W0 : (z == 1) ? W1 : (z == 2) ? W2 : W3;
  unsigned short* T = (z == 0) ? T0 : (z == 1) ? T1 : (z == 2) ? T2 : T3;
  const int n0 = blockIdx.x * 32, k0 = blockIdx.y * 32;
  const int tx = threadIdx.x, ty = threadIdx.y;  // 32 x 8
#pragma unroll
  for (int i = 0; i < 4; ++i)
    t[ty + 8 * i][tx] = W[(size_t)(k0 + ty + 8 * i) * D_MODEL + n0 + tx];
  __syncthreads();
#pragma unroll
  for (int i = 0; i < 4; ++i)
    T[(size_t)(n0 + ty + 8 * i) * D_MODEL + k0 + tx] = f2bf(t[tx][ty + 8 * i]);
}

// ---------------------------------------------------------------------------
// bf16 GEMM: C[M=8192][N=1024] = A[M][K=1024] @ Wt[N][K]^T + bias
// 128x128 tile, BK=64, 4 waves, dbuf LDS + T4 counted-vmcnt (R7-verified) +
// bijective XCD-chunked swizzle. N=1024 ONLY: per-XCD working set is
// A-chunk 2MB + B-chunk 2MB = 4MB = exactly one XCD's L2. (R8 lesson:
// fusing Q+K to N=2048 needs >= 5.7MB/XCD -> L2 thrash, 80us vs 2x20us.)
// mode 0: out bf16 [b,h,s,d] (Q,K); mode 1: out bf16 [b,h,d,s] (V^T);
// mode 2: out fp32 [m][n] (final projection)
// ---------------------------------------------------------------------------
__global__ __launch_bounds__(256) void gemm128(
    const unsigned short* __restrict__ A, const unsigned short* __restrict__ Bt,
    const float* __restrict__ bias, unsigned short* __restrict__ outb,
    float* __restrict__ outf, const int mode) {
  __shared__ __align__(16) unsigned short Alds[2 * 128 * 64];
  __shared__ __align__(16) unsigned short Blds[2 * 128 * 64];
  const int tid = threadIdx.x;
  const int lane = tid & 63;
  const int w = tid >> 6;
  const int wr = w >> 1, wc = w & 1;

  // bijective XCD-chunked swizzle (grid (8,64) = 512 blocks; 512 % 8 == 0)
  int flat = (int)blockIdx.x + 8 * (int)blockIdx.y;
  flat = (flat & 7) * 64 + (flat >> 3);
  const int n0 = (flat & 7) * 128;
  const int m0 = (flat >> 3) * 128;

  const int srow = tid >> 3, sslot = tid & 7;

  auto stage = [&](int kk, int buf) {
#pragma unroll
    for (int i = 0; i < 4; ++i) {
      const int r = srow + 32 * i;
      const int gc = kk * 64 + ((sslot ^ (r & 7)) << 3);
      gll16(A + (size_t)(m0 + r) * D_MODEL + gc, &Alds[buf * 8192 + tid * 8 + i * 2048]);
      gll16(Bt + (size_t)(n0 + r) * D_MODEL + gc, &Blds[buf * 8192 + tid * 8 + i * 2048]);
    }
  };

  f32x4 acc[4][4] = {};

  // prologue: stage K-tiles 0 and 1
  stage(0, 0);
  stage(1, 1);

  const int NK = D_MODEL / 64;  // 16
  for (int kk = 0; kk < NK; ++kk) {
    const int cur = kk & 1;
    // tile kk's 8 loads complete; tile kk+1's 8 may stay in flight (T4)
    if (kk + 1 < NK) asm volatile("s_waitcnt vmcnt(8)" ::: "memory");
    else             asm volatile("s_waitcnt vmcnt(0)" ::: "memory");
    __builtin_amdgcn_s_barrier();
    asm volatile("" ::: "memory");

    const unsigned short* Al = &Alds[cur * 8192];
    const unsigned short* Bl = &Blds[cur * 8192];
#pragma unroll
    for (int kf = 0; kf < 2; ++kf) {
      const int sb = kf * 4 + (lane >> 4);
      bf16x8 a[4], b[4];
#pragma unroll
      for (int m = 0; m < 4; ++m) {
        const int row = wr * 64 + m * 16 + (lane & 15);
        a[m] = *(const bf16x8*)&Al[row * 64 + ((sb ^ (row & 7)) << 3)];
      }
#pragma unroll
      for (int n = 0; n < 4; ++n) {
        const int row = wc * 64 + n * 16 + (lane & 15);
        b[n] = *(const bf16x8*)&Bl[row * 64 + ((sb ^ (row & 7)) << 3)];
      }
#pragma unroll
      for (int m = 0; m < 4; ++m)
#pragma unroll
        for (int n = 0; n < 4; ++n)
          acc[m][n] = __builtin_amdgcn_mfma_f32_16x16x32_bf16(a[m], b[n], acc[m][n], 0, 0, 0);
    }

    asm volatile("" ::: "memory");
    __builtin_amdgcn_s_barrier();  // all waves done reading buf[cur]

    if (kk + 2 < NK) stage(kk + 2, cur);  // overwrite just-freed buffer
  }

#pragma unroll
  for (int m = 0; m < 4; ++m) {
    const int rb = m0 + wr * 64 + m * 16 + ((lane >> 4) << 2);
#pragma unroll
    for (int n = 0; n < 4; ++n) {
      const int col = n0 + wc * 64 + n * 16 + (lane & 15);
      const float bv = bias[col];
#pragma unroll
      for (int j = 0; j < 4; ++j) {
        const int row = rb + j;
        const float v = acc[m][n][j] + bv;
        if (mode == 2) {
          outf[(size_t)row * D_MODEL + col] = v;
        } else {
          const int b_ = row >> 11, s_ = row & (SEQ - 1);
          const int h_ = col >> 6, d_ = col & (DK - 1);
          size_t idx;
          if (mode == 0) idx = (((size_t)(b_ * NH + h_)) * SEQ + s_) * DK + d_;
          else           idx = (((size_t)(b_ * NH + h_)) * DK + d_) * SEQ + s_;
          outb[idx] = f2bf(v);
        }
      }
    }
  }
}

// ---------------------------------------------------------------------------
// causal flash attention (R8-verified): scores in log2 domain (ln2^-1 folded
// into Q pre-scale) + single-instruction v_exp_f32; T4 counted-vmcnt dbuf.
// Block = (bh, strip): 128 q-rows, 4 waves x 32 rows (lane&31 -> q-row).
// ---------------------------------------------------------------------------
__global__ __launch_bounds__(256, 4) void attn4w(
    const unsigned short* __restrict__ Q, const unsigned short* __restrict__ K,
    const unsigned short* __restrict__ Vt, unsigned short* __restrict__ O) {
  __shared__ __align__(16) unsigned short Klds[2 * 64 * 64];
  __shared__ __align__(16) unsigned short Vlds[2 * 64 * 64];

  const int tid = threadIdx.x, lane = tid & 63, w = tid >> 6;
  const int lq = lane & 31, hi = lane >> 5;
  const int bh = blockIdx.x;
  const int strip = 15 - (int)blockIdx.y;  // heavy strips dispatched first
  const size_t qkbase = (size_t)bh * SEQ * DK;
  const size_t vbase = (size_t)bh * DK * SEQ;
  const int srow = tid >> 3, sslot = tid & 7;
  const int b_ = bh >> 4, h_ = bh & (NH - 1);

  const int q0 = strip * 128;
  const int qw0 = q0 + w * 32;  // wave's first q-row
  const int qg = qw0 + lq;      // this lane's q-row
  const int n = 2 * strip + 2;  // kv phases (64 each)

  // Q as B-operand frags: col=lane&31 -> q, k = hi*8 + ks*16 + e.
  // Pre-scaled by log2(e)/sqrt(DK): QK^T lands directly in log2 domain.
  bf16x8 qb[4];
  {
    const float QSCALE = 0.125f * 1.44269504f;
    const unsigned short* qp = Q + qkbase + (size_t)qg * DK + hi * 8;
#pragma unroll
    for (int ks = 0; ks < 4; ++ks) {
      qb[ks] = *(const bf16x8*)(qp + ks * 16);
#pragma unroll
      for (int e = 0; e < 8; ++e)
        qb[ks][e] = (__bf16)((float)qb[ks][e] * QSCALE);
    }
  }

  float m = -3e38f, l = 0.f;
  f32x16 o0 = {}, o1 = {};

  // prologue: stage tiles 0 and 1 (n >= 2 always)
#pragma unroll
  for (int i = 0; i < 2; ++i) {
    const int r = srow + 32 * i;
    const int sc = (sslot ^ (r & 7)) << 3;
    gll16(K + qkbase + (size_t)r * DK + sc, &Klds[tid * 8 + i * 2048]);
    gll16(Vt + vbase + (size_t)r * SEQ + sc, &Vlds[tid * 8 + i * 2048]);
  }
#pragma unroll
  for (int i = 0; i < 2; ++i) {
    const int r = srow + 32 * i;
    const int sc = (sslot ^ (r & 7)) << 3;
    gll16(K + qkbase + (size_t)(64 + r) * DK + sc, &Klds[4096 + tid * 8 + i * 2048]);
    gll16(Vt + vbase + (size_t)r * SEQ + 64 + sc, &Vlds[4096 + tid * 8 + i * 2048]);
  }

  for (int jt = 0; jt < n; ++jt) {
    const int cur = jt & 1;
    if (jt + 1 < n) asm volatile("s_waitcnt vmcnt(4)" ::: "memory");
    else            asm volatile("s_waitcnt vmcnt(0)" ::: "memory");
    __builtin_amdgcn_s_barrier();
    asm volatile("" ::: "memory");

    if (64 * jt < qw0 + 32) {  // skip fully-masked phases
      const unsigned short* Kl = &Klds[cur * 4096];
      const unsigned short* Vl = &Vlds[cur * 4096];

      // S^T (log2 domain) = K·Q^T : st0 = kv 0..31, st1 = kv 32..63
      f32x16 st0 = {}, st1 = {};
      __builtin_amdgcn_s_setprio(1);
#pragma unroll
      for (int ks = 0; ks < 4; ++ks) {
        const int so = ((ks * 2 + hi) ^ (lq & 7)) << 3;
        const bf16x8 ka0 = *(const bf16x8*)&Kl[lq * 64 + so];
        const bf16x8 ka1 = *(const bf16x8*)&Kl[(32 + lq) * 64 + so];
        st0 = __builtin_amdgcn_mfma_f32_32x32x16_bf16(ka0, qb[ks], st0, 0, 0, 0);
        st1 = __builtin_amdgcn_mfma_f32_32x32x16_bf16(ka1, qb[ks], st1, 0, 0, 0);
      }
      __builtin_amdgcn_s_setprio(0);

      // causal mask: kv = 64*jt + kvb*32 + (r&3)+8*(r>>2)+4*hi  vs  q-row qg
      if (64 * jt + 63 > qw0) {
        const int rb = 64 * jt + 4 * hi - qg;
#pragma unroll
        for (int r = 0; r < 16; ++r) {
          const int crow0 = (r & 3) + 8 * (r >> 2);
          if (crow0 + rb > 0)      st0[r] = -3e38f;
          if (crow0 + 32 + rb > 0) st1[r] = -3e38f;
        }
      }

      // row max: lane-local tree + one cross-half exchange
      float tmax[8];
#pragma unroll
      for (int r = 0; r < 8; ++r)
        tmax[r] = fmaxf(fmaxf(st0[r], st0[r + 8]), fmaxf(st1[r], st1[r + 8]));
      float mx = fmaxf(fmaxf(fmaxf(tmax[0], tmax[1]), fmaxf(tmax[2], tmax[3])),
                       fmaxf(fmaxf(tmax[4], tmax[5]), fmaxf(tmax[6], tmax[7])));
      mx = fmaxf(mx, __shfl_xor(mx, 32));

      // defer-max (T13): threshold 8*log2e in log2 domain
      if (__any((int)(mx > m + 11.5416f))) {
        const float mnew = fmaxf(m, mx);
        const float alpha = exp2fast(m - mnew);
        m = mnew;
        l *= alpha;
#pragma unroll
        for (int r = 0; r < 16; ++r) { o0[r] *= alpha; o1[r] *= alpha; }
      }

      // P = 2^(S - m): one sub + one v_exp per element
#pragma unroll
      for (int r = 0; r < 16; ++r) {
        st0[r] = exp2fast(st0[r] - m);
        st1[r] = exp2fast(st1[r] - m);
      }

      // row sum: tree + cross-half
      float tsum[8];
#pragma unroll
      for (int r = 0; r < 8; ++r)
        tsum[r] = (st0[r] + st0[r + 8]) + (st1[r] + st1[r + 8]);
      float rs = ((tsum[0] + tsum[1]) + (tsum[2] + tsum[3])) +
                 ((tsum[4] + tsum[5]) + (tsum[6] + tsum[7]));
      rs += __shfl_xor(rs, 32);
      l += rs;

      // P -> bf16 B-frags via cvt_pk + permlane32_swap (T12; distinct asm
      // outputs -> no aliasing hazard)
      bf16x8 pb[4];
#pragma unroll
      for (int ks = 0; ks < 4; ++ks) {
        const int base = (ks & 1) * 8;
        float p0, p1, p2, p3, p4, p5, p6, p7;
        if (ks < 2) {
          p0 = st0[base + 0]; p1 = st0[base + 1]; p2 = st0[base + 2]; p3 = st0[base + 3];
          p4 = st0[base + 4]; p5 = st0[base + 5]; p6 = st0[base + 6]; p7 = st0[base + 7];
        } else {
          p0 = st1[base + 0]; p1 = st1[base + 1]; p2 = st1[base + 2]; p3 = st1[base + 3];
          p4 = st1[base + 4]; p5 = st1[base + 5]; p6 = st1[base + 6]; p7 = st1[base + 7];
        }
        int a0 = cvtpk(p0, p1), a1 = cvtpk(p2, p3);
        int a2 = cvtpk(p4, p5), a3 = cvtpk(p6, p7);
        pl32swap(a0, a2);
        pl32swap(a1, a3);
        union { int i[4]; bf16x8 v; } u;
        u.i[0] = a0; u.i[1] = a1; u.i[2] = a2; u.i[3] = a3;
        pb[ks] = u.v;
      }

      // O^T += V^T·P^T   (A = Vt rows d from LDS, B = pb)
      __builtin_amdgcn_s_setprio(1);
#pragma unroll
      for (int ks = 0; ks < 4; ++ks) {
        const int so = ((ks * 2 + hi) ^ (lq & 7)) << 3;
        const bf16x8 va0 = *(const bf16x8*)&Vl[lq * 64 + so];
        const bf16x8 va1 = *(const bf16x8*)&Vl[(32 + lq) * 64 + so];
        o0 = __builtin_amdgcn_mfma_f32_32x32x16_bf16(va0, pb[ks], o0, 0, 0, 0);
        o1 = __builtin_amdgcn_mfma_f32_32x32x16_bf16(va1, pb[ks], o1, 0, 0, 0);
      }
      __builtin_amdgcn_s_setprio(0);
    }

    asm volatile("" ::: "memory");
    __builtin_amdgcn_s_barrier();  // all waves done reading buf[cur]

    // stage tile jt+2 into buf[cur] (just freed)
    if (jt + 2 < n) {
      const int kv0 = (jt + 2) * 64;
#pragma unroll
      for (int i = 0; i < 2; ++i) {
        const int r = srow + 32 * i;
        const int sc = (sslot ^ (r & 7)) << 3;
        gll16(K + qkbase + (size_t)(kv0 + r) * DK + sc,
              &Klds[cur * 4096 + tid * 8 + i * 2048]);
        gll16(Vt + vbase + (size_t)r * SEQ + kv0 + sc,
              &Vlds[cur * 4096 + tid * 8 + i * 2048]);
      }
    }
  }

  // epilogue: O[b*s][h*64+d]; lane owns q-row qg; o rows are d.
  const float rl = 1.0f / l;
  unsigned short* orow = O + (size_t)(b_ * SEQ + qg) * D_MODEL + h_ * DK;
#pragma unroll
  for (int g = 0; g < 4; ++g) {
    us4v pk0, pk1;
#pragma unroll
    for (int j = 0; j < 4; ++j) {
      pk0[j] = f2bf(o0[4 * g + j] * rl);
      pk1[j] = f2bf(o1[4 * g + j] * rl);
    }
    const int d0 = 8 * g + 4 * hi;
    *(us4v*)&orow[d0] = pk0;
    *(us4v*)&orow[32 + d0] = pk1;
  }
}

// ---------------------------------------------------------------------------
extern "C" void kernel_launch(void* const* d_in, const int* in_sizes, int n_in,
                              void* d_out, int out_size, void* d_ws, size_t ws_size,
                              hipStream_t stream) {
  const float* ctx = (const float*)d_in[0];
  const float* val = (const float*)d_in[1];
  // d_in[2] = mask: statically causal triu(k=1); handled analytically.
  const float* Wq = (const float*)d_in[3];
  const float* bq = (const float*)d_in[4];
  const float* Wk = (const float*)d_in[5];
  const float* bk = (const float*)d_in[6];
  const float* Wv = (const float*)d_in[7];
  const float* bv = (const float*)d_in[8];
  const float* Wo = (const float*)d_in[9];
  const float* bo = (const float*)d_in[10];

  unsigned short* ws = (unsigned short*)d_ws;
  const size_t XSZ = (size_t)BATCH * SEQ * D_MODEL;  // 8388608
  const size_t WSZ = (size_t)D_MODEL * D_MODEL;      // 1048576
  unsigned short* Xc  = ws;                // Xc,Xv adjacent (cvtbf2 target)
  unsigned short* Xv  = Xc + XSZ;
  unsigned short* Wqt = Xv + XSZ;
  unsigned short* Wkt = Wqt + WSZ;
  unsigned short* Wvt = Wkt + WSZ;
  unsigned short* Wot = Wvt + WSZ;
  unsigned short* Qb  = Wot + WSZ;
  unsigned short* Kb  = Qb + XSZ;
  unsigned short* Vtb = Kb + XSZ;
  unsigned short* Ob  = Vtb + XSZ;

  cvtbf2<<<2048, 256, 0, stream>>>(ctx, val, Xc, (int)XSZ);
  wtrans<<<dim3(32, 32, 4), dim3(32, 8), 0, stream>>>(Wq, Wk, Wv, Wo, Wqt, Wkt, Wvt, Wot);

  dim3 gg(D_MODEL / 128, BATCH * SEQ / 128);  // (8, 64) = 512 blocks
  gemm128<<<gg, 256, 0, stream>>>(Xc, Wqt, bq, Qb, nullptr, 0);
  gemm128<<<gg, 256, 0, stream>>>(Xc, Wkt, bk, Kb, nullptr, 0);
  gemm128<<<gg, 256, 0, stream>>>(Xv, Wvt, bv, Vtb, nullptr, 1);

  // 1024 blocks: x = bh (64, %8 -> XCD locality), y = 16 strips heavy-first
  attn4w<<<dim3(BATCH * NH, 16), 256, 0, stream>>>(Qb, Kb, Vtb, Ob);

  gemm128<<<gg, 256, 0, stream>>>(Ob, Wot, bo, nullptr, (float*)d_out, 2);
}

// Round 10
// 169.869 us; speedup vs baseline: 1.7312x; 1.0602x over previous
//
#include <hip/hip_runtime.h>
#include <stdint.h>

#define D_MODEL 1024
#define SEQ 2048
#define BATCH 4
#define NH 16
#define DK 64

typedef float f32x4 __attribute__((ext_vector_type(4)));
typedef float f32x16 __attribute__((ext_vector_type(16)));
typedef __bf16 bf16x8 __attribute__((ext_vector_type(8)));
typedef unsigned short us4v __attribute__((ext_vector_type(4)));

__device__ __forceinline__ unsigned short f2bf(float f) {
  union { float f; unsigned u; } x; x.f = f;
  unsigned r = x.u + 0x7FFFu + ((x.u >> 16) & 1u);  // RNE
  return (unsigned short)(r >> 16);
}

// async global->LDS, 16B per lane
__device__ __forceinline__ void gll16(const void* g, void* l) {
  __builtin_amdgcn_global_load_lds(
      (__attribute__((address_space(1))) void*)g,
      (__attribute__((address_space(3))) void*)l, 16, 0, 0);
}

// packed f32x2 -> bf16x2 (RNE), one VALU op
__device__ __forceinline__ int cvtpk(float lo, float hi) {
  int r;
  asm("v_cvt_pk_bf16_f32 %0, %1, %2" : "=v"(r) : "v"(lo), "v"(hi));
  return r;
}
// v_permlane32_swap_b32: a[32:63] <-> b[0:31]. Safe ONLY with provably-
// distinct registers (R3 bug: copy-coalescing emitted swap v5,v5).
__device__ __forceinline__ void pl32swap(int& a, int& b) {
  asm volatile("v_permlane32_swap_b32 %0, %1" : "+v"(a), "+v"(b));
}
// cross-half (lane i <-> i+32) max via permlane32_swap. The v_mov is an
// OPAQUE asm output -> never copy-coalesced with its source, so the swap's
// two operands are guaranteed distinct physical registers.
__device__ __forceinline__ float xmax32(float x) {
  int a = __float_as_int(x), b;
  asm volatile("v_mov_b32 %0, %1" : "=v"(b) : "v"(a));
  pl32swap(a, b);
  return fmaxf(__int_as_float(a), __int_as_float(b));
}
// single-instruction 2^x (vs OCML exp2f's multi-op sequence)
__device__ __forceinline__ float exp2fast(float x) {
  float r;
  asm("v_exp_f32 %0, %1" : "=v"(r) : "v"(x));
  return r;
}

// ---------------------------------------------------------------------------
// fp32 -> bf16 convert, two segments in one launch (Xc,Xv are adjacent)
// ---------------------------------------------------------------------------
__global__ void cvtbf2(const float* __restrict__ a, const float* __restrict__ b,
                       unsigned short* __restrict__ out, const int nseg) {
  const int t = blockIdx.x * blockDim.x + threadIdx.x;
  const int stride = gridDim.x * blockDim.x;
  for (int i = t * 4; i < 2 * nseg; i += stride * 4) {
    const float* src = (i < nseg) ? &a[i] : &b[i - nseg];
    const float4 v = *(const float4*)src;
    us4v o;
    o[0] = f2bf(v.x); o[1] = f2bf(v.y); o[2] = f2bf(v.z); o[3] = f2bf(v.w);
    *(us4v*)&out[i] = o;
  }
}

// ---------------------------------------------------------------------------
// weight transpose + convert: W[k][n] fp32 -> Wt[n][k] bf16   (1024x1024, x4)
// ---------------------------------------------------------------------------
__global__ void wtrans(const float* __restrict__ W0, const float* __restrict__ W1,
                       const float* __restrict__ W2, const float* __restrict__ W3,
                       unsigned short* __restrict__ T0, unsigned short* __restrict__ T1,
                       unsigned short* __restrict__ T2, unsigned short* __restrict__ T3) {
  __shared__ float t[32][33];
  const int z = blockIdx.z;
  const float* W = (z == 0) ? W0 : (z == 1) ? W1 : (z == 2) ? W2 : W3;
  unsigned short* T = (z == 0) ? T0 : (z == 1) ? T1 : (z == 2) ? T2 : T3;
  const int n0 = blockIdx.x * 32, k0 = blockIdx.y * 32;
  const int tx = threadIdx.x, ty = threadIdx.y;  // 32 x 8
#pragma unroll
  for (int i = 0; i < 4; ++i)
    t[ty + 8 * i][tx] = W[(size_t)(k0 + ty + 8 * i) * D_MODEL + n0 + tx];
  __syncthreads();
#pragma unroll
  for (int i = 0; i < 4; ++i)
    T[(size_t)(n0 + ty + 8 * i) * D_MODEL + k0 + tx] = f2bf(t[tx][ty + 8 * i]);
}

// ---------------------------------------------------------------------------
// bf16 GEMM body: C[M=8192][N=1024] = A @ Wt^T + bias.  128x128 tile, BK=64,
// 4 waves, dbuf LDS + T4 counted-vmcnt + bijective XCD-chunked swizzle.
// N=1024 only (R8 lesson: N=2048 B-panel blows the 4MB/XCD L2).
// mode 0: out bf16 [b,h,s,d]; mode 1: out bf16 [b,h,d,s]; mode 2: fp32 [m][n]
// ---------------------------------------------------------------------------
__device__ __forceinline__ void gemm_body(
    const unsigned short* __restrict__ A, const unsigned short* __restrict__ Bt,
    const float* __restrict__ bias, unsigned short* __restrict__ outb,
    float* __restrict__ outf, const int mode,
    unsigned short* Alds, unsigned short* Blds) {
  const int tid = threadIdx.x;
  const int lane = tid & 63;
  const int w = tid >> 6;
  const int wr = w >> 1, wc = w & 1;

  // bijective XCD-chunked swizzle (grid (8,64) per slice = 512; 512 % 8 == 0)
  int flat = (int)blockIdx.x + 8 * (int)blockIdx.y;
  flat = (flat & 7) * 64 + (flat >> 3);
  const int n0 = (flat & 7) * 128;
  const int m0 = (flat >> 3) * 128;

  const int srow = tid >> 3, sslot = tid & 7;

  auto stage = [&](int kk, int buf) {
#pragma unroll
    for (int i = 0; i < 4; ++i) {
      const int r = srow + 32 * i;
      const int gc = kk * 64 + ((sslot ^ (r & 7)) << 3);
      gll16(A + (size_t)(m0 + r) * D_MODEL + gc, &Alds[buf * 8192 + tid * 8 + i * 2048]);
      gll16(Bt + (size_t)(n0 + r) * D_MODEL + gc, &Blds[buf * 8192 + tid * 8 + i * 2048]);
    }
  };

  f32x4 acc[4][4] = {};

  stage(0, 0);
  stage(1, 1);

  const int NK = D_MODEL / 64;  // 16
  for (int kk = 0; kk < NK; ++kk) {
    const int cur = kk & 1;
    if (kk + 1 < NK) asm volatile("s_waitcnt vmcnt(8)" ::: "memory");
    else             asm volatile("s_waitcnt vmcnt(0)" ::: "memory");
    __builtin_amdgcn_s_barrier();
    asm volatile("" ::: "memory");

    const unsigned short* Al = &Alds[cur * 8192];
    const unsigned short* Bl = &Blds[cur * 8192];
#pragma unroll
    for (int kf = 0; kf < 2; ++kf) {
      const int sb = kf * 4 + (lane >> 4);
      bf16x8 a[4], b[4];
#pragma unroll
      for (int m = 0; m < 4; ++m) {
        const int row = wr * 64 + m * 16 + (lane & 15);
        a[m] = *(const bf16x8*)&Al[row * 64 + ((sb ^ (row & 7)) << 3)];
      }
#pragma unroll
      for (int n = 0; n < 4; ++n) {
        const int row = wc * 64 + n * 16 + (lane & 15);
        b[n] = *(const bf16x8*)&Bl[row * 64 + ((sb ^ (row & 7)) << 3)];
      }
#pragma unroll
      for (int m = 0; m < 4; ++m)
#pragma unroll
        for (int n = 0; n < 4; ++n)
          acc[m][n] = __builtin_amdgcn_mfma_f32_16x16x32_bf16(a[m], b[n], acc[m][n], 0, 0, 0);
    }

    asm volatile("" ::: "memory");
    __builtin_amdgcn_s_barrier();  // all waves done reading buf[cur]

    if (kk + 2 < NK) stage(kk + 2, cur);
  }

#pragma unroll
  for (int m = 0; m < 4; ++m) {
    const int rb = m0 + wr * 64 + m * 16 + ((lane >> 4) << 2);
#pragma unroll
    for (int n = 0; n < 4; ++n) {
      const int col = n0 + wc * 64 + n * 16 + (lane & 15);
      const float bv = bias[col];
#pragma unroll
      for (int j = 0; j < 4; ++j) {
        const int row = rb + j;
        const float v = acc[m][n][j] + bv;
        if (mode == 2) {
          outf[(size_t)row * D_MODEL + col] = v;
        } else {
          const int b_ = row >> 11, s_ = row & (SEQ - 1);
          const int h_ = col >> 6, d_ = col & (DK - 1);
          size_t idx;
          if (mode == 0) idx = (((size_t)(b_ * NH + h_)) * SEQ + s_) * DK + d_;
          else           idx = (((size_t)(b_ * NH + h_)) * DK + d_) * SEQ + s_;
          outb[idx] = f2bf(v);
        }
      }
    }
  }
}

// merged Q/K/V projections in one launch: grid (8, 64, 3); z slices are
// dispatched sequentially so per-XCD L2 set stays ~4MB per slice.
__global__ __launch_bounds__(256) void gemmQKV(
    const unsigned short* __restrict__ Xc, const unsigned short* __restrict__ Xv,
    const unsigned short* __restrict__ Wqt, const unsigned short* __restrict__ Wkt,
    const unsigned short* __restrict__ Wvt,
    const float* __restrict__ bq, const float* __restrict__ bk,
    const float* __restrict__ bv,
    unsigned short* __restrict__ Qb, unsigned short* __restrict__ Kb,
    unsigned short* __restrict__ Vtb) {
  __shared__ __align__(16) unsigned short Alds[2 * 128 * 64];
  __shared__ __align__(16) unsigned short Blds[2 * 128 * 64];
  const int z = blockIdx.z;
  const unsigned short* A = (z == 2) ? Xv : Xc;
  const unsigned short* Bt = (z == 0) ? Wqt : (z == 1) ? Wkt : Wvt;
  const float* bias = (z == 0) ? bq : (z == 1) ? bk : bv;
  unsigned short* outb = (z == 0) ? Qb : (z == 1) ? Kb : Vtb;
  gemm_body(A, Bt, bias, outb, nullptr, (z == 2) ? 1 : 0, Alds, Blds);
}

__global__ __launch_bounds__(256) void gemmO(
    const unsigned short* __restrict__ A, const unsigned short* __restrict__ Bt,
    const float* __restrict__ bias, float* __restrict__ outf) {
  __shared__ __align__(16) unsigned short Alds[2 * 128 * 64];
  __shared__ __align__(16) unsigned short Blds[2 * 128 * 64];
  gemm_body(A, Bt, bias, nullptr, outf, 2, Alds, Blds);
}

// ---------------------------------------------------------------------------
// causal flash attention. R10: 3-slot LDS ring -> ONE barrier per phase.
// Race-proof: stage(t+2) targets slot (t+2)%3 == (t-1)%3, whose last reader
// (compute(t-1)) finished before this phase's barrier; per-wave vmcnt(4)
// before the barrier publishes tile t (each wave drains its own loads, the
// barrier makes it block-wide). Loads never drain to 0 in-loop (T4).
// Scores in log2 domain; v_exp_f32; cross-half max via permlane32_swap;
// l kept per-half, combined once in epilogue.
// Block = (bh, strip): 128 q-rows, 4 waves x 32 rows (lane&31 -> q-row).
// ---------------------------------------------------------------------------
__global__ __launch_bounds__(256, 3) void attn4w(
    const unsigned short* __restrict__ Q, const unsigned short* __restrict__ K,
    const unsigned short* __restrict__ Vt, unsigned short* __restrict__ O) {
  __shared__ __align__(16) unsigned short Klds[3 * 64 * 64];
  __shared__ __align__(16) unsigned short Vlds[3 * 64 * 64];

  const int tid = threadIdx.x, lane = tid & 63, w = tid >> 6;
  const int lq = lane & 31, hi = lane >> 5;
  const int bh = blockIdx.x;
  const int strip = 15 - (int)blockIdx.y;  // heavy strips dispatched first
  const size_t qkbase = (size_t)bh * SEQ * DK;
  const size_t vbase = (size_t)bh * DK * SEQ;
  const int srow = tid >> 3, sslot = tid & 7;
  const int b_ = bh >> 4, h_ = bh & (NH - 1);

  const int q0 = strip * 128;
  const int qw0 = q0 + w * 32;  // wave's first q-row
  const int qg = qw0 + lq;      // this lane's q-row
  const int n = 2 * strip + 2;  // kv phases (64 each)

  auto stageKV = [&](int t, int slot) {
#pragma unroll
    for (int i = 0; i < 2; ++i) {
      const int r = srow + 32 * i;
      const int sc = (sslot ^ (r & 7)) << 3;
      gll16(K + qkbase + (size_t)(t * 64 + r) * DK + sc,
            &Klds[slot * 4096 + tid * 8 + i * 2048]);
      gll16(Vt + vbase + (size_t)r * SEQ + t * 64 + sc,
            &Vlds[slot * 4096 + tid * 8 + i * 2048]);
    }
  };

  // Q as B-operand frags: col=lane&31 -> q, k = hi*8 + ks*16 + e.
  // Pre-scaled by log2(e)/sqrt(DK): QK^T lands directly in log2 domain.
  bf16x8 qb[4];
  {
    const float QSCALE = 0.125f * 1.44269504f;
    const unsigned short* qp = Q + qkbase + (size_t)qg * DK + hi * 8;
#pragma unroll
    for (int ks = 0; ks < 4; ++ks) {
      qb[ks] = *(const bf16x8*)(qp + ks * 16);
#pragma unroll
      for (int e = 0; e < 8; ++e)
        qb[ks][e] = (__bf16)((float)qb[ks][e] * QSCALE);
    }
  }

  float m = -3e38f, l = 0.f;  // l is per-half; combined in epilogue
  f32x16 o0 = {}, o1 = {};

  // prologue: stage tiles 0,1 into slots 0,1
  stageKV(0, 0);
  stageKV(1, 1);

  for (int jt = 0; jt < n; ++jt) {
    const int slot = jt % 3;
    // tile jt complete after this wait (tile jt+1's 4 loads stay in flight)
    if (jt + 1 < n) asm volatile("s_waitcnt vmcnt(4)" ::: "memory");
    else            asm volatile("s_waitcnt vmcnt(0)" ::: "memory");
    __builtin_amdgcn_s_barrier();  // single barrier per phase
    asm volatile("" ::: "memory");

    // stage tile jt+2 into slot (jt+2)%3 == (jt-1)%3 (freed: its last
    // reader was compute(jt-1), which preceded the barrier above)
    if (jt + 2 < n) stageKV(jt + 2, (jt + 2) % 3);

    if (64 * jt < qw0 + 32) {  // skip fully-masked phases
      const unsigned short* Kl = &Klds[slot * 4096];
      const unsigned short* Vl = &Vlds[slot * 4096];

      // S^T (log2 domain) = K·Q^T : st0 = kv 0..31, st1 = kv 32..63
      f32x16 st0 = {}, st1 = {};
      __builtin_amdgcn_s_setprio(1);
#pragma unroll
      for (int ks = 0; ks < 4; ++ks) {
        const int so = ((ks * 2 + hi) ^ (lq & 7)) << 3;
        const bf16x8 ka0 = *(const bf16x8*)&Kl[lq * 64 + so];
        const bf16x8 ka1 = *(const bf16x8*)&Kl[(32 + lq) * 64 + so];
        st0 = __builtin_amdgcn_mfma_f32_32x32x16_bf16(ka0, qb[ks], st0, 0, 0, 0);
        st1 = __builtin_amdgcn_mfma_f32_32x32x16_bf16(ka1, qb[ks], st1, 0, 0, 0);
      }
      __builtin_amdgcn_s_setprio(0);

      // causal mask: kv = 64*jt + kvb*32 + (r&3)+8*(r>>2)+4*hi  vs  q-row qg
      if (64 * jt + 63 > qw0) {
        const int rb = 64 * jt + 4 * hi - qg;
#pragma unroll
        for (int r = 0; r < 16; ++r) {
          const int crow0 = (r & 3) + 8 * (r >> 2);
          if (crow0 + rb > 0)      st0[r] = -3e38f;
          if (crow0 + 32 + rb > 0) st1[r] = -3e38f;
        }
      }

      // row max: lane-local tree + permlane cross-half exchange
      float tmax[8];
#pragma unroll
      for (int r = 0; r < 8; ++r)
        tmax[r] = fmaxf(fmaxf(st0[r], st0[r + 8]), fmaxf(st1[r], st1[r + 8]));
      float mx = fmaxf(fmaxf(fmaxf(tmax[0], tmax[1]), fmaxf(tmax[2], tmax[3])),
                       fmaxf(fmaxf(tmax[4], tmax[5]), fmaxf(tmax[6], tmax[7])));
      mx = xmax32(mx);

      // defer-max (T13): threshold 8*log2e in log2 domain
      if (__any((int)(mx > m + 11.5416f))) {
        const float mnew = fmaxf(m, mx);
        const float alpha = exp2fast(m - mnew);  // uniform across halves
        m = mnew;
        l *= alpha;
#pragma unroll
        for (int r = 0; r < 16; ++r) { o0[r] *= alpha; o1[r] *= alpha; }
      }

      // P = 2^(S - m)
#pragma unroll
      for (int r = 0; r < 16; ++r) {
        st0[r] = exp2fast(st0[r] - m);
        st1[r] = exp2fast(st1[r] - m);
      }

      // row sum: lane-local tree only; cross-half combine deferred to epilogue
      float tsum[8];
#pragma unroll
      for (int r = 0; r < 8; ++r)
        tsum[r] = (st0[r] + st0[r + 8]) + (st1[r] + st1[r + 8]);
      l += ((tsum[0] + tsum[1]) + (tsum[2] + tsum[3])) +
           ((tsum[4] + tsum[5]) + (tsum[6] + tsum[7]));

      // P -> bf16 B-frags via cvt_pk + permlane32_swap (T12; distinct asm
      // outputs -> no aliasing hazard)
      bf16x8 pb[4];
#pragma unroll
      for (int ks = 0; ks < 4; ++ks) {
        const int base = (ks & 1) * 8;
        float p0, p1, p2, p3, p4, p5, p6, p7;
        if (ks < 2) {
          p0 = st0[base + 0]; p1 = st0[base + 1]; p2 = st0[base + 2]; p3 = st0[base + 3];
          p4 = st0[base + 4]; p5 = st0[base + 5]; p6 = st0[base + 6]; p7 = st0[base + 7];
        } else {
          p0 = st1[base + 0]; p1 = st1[base + 1]; p2 = st1[base + 2]; p3 = st1[base + 3];
          p4 = st1[base + 4]; p5 = st1[base + 5]; p6 = st1[base + 6]; p7 = st1[base + 7];
        }
        int a0 = cvtpk(p0, p1), a1 = cvtpk(p2, p3);
        int a2 = cvtpk(p4, p5), a3 = cvtpk(p6, p7);
        pl32swap(a0, a2);
        pl32swap(a1, a3);
        union { int i[4]; bf16x8 v; } u;
        u.i[0] = a0; u.i[1] = a1; u.i[2] = a2; u.i[3] = a3;
        pb[ks] = u.v;
      }

      // O^T += V^T·P^T   (A = Vt rows d from LDS, B = pb)
      __builtin_amdgcn_s_setprio(1);
#pragma unroll
      for (int ks = 0; ks < 4; ++ks) {
        const int so = ((ks * 2 + hi) ^ (lq & 7)) << 3;
        const bf16x8 va0 = *(const bf16x8*)&Vl[lq * 64 + so];
        const bf16x8 va1 = *(const bf16x8*)&Vl[(32 + lq) * 64 + so];
        o0 = __builtin_amdgcn_mfma_f32_32x32x16_bf16(va0, pb[ks], o0, 0, 0, 0);
        o1 = __builtin_amdgcn_mfma_f32_32x32x16_bf16(va1, pb[ks], o1, 0, 0, 0);
      }
      __builtin_amdgcn_s_setprio(0);
    }
    asm volatile("" ::: "memory");
  }

  // epilogue: combine per-half l, then O[b*s][h*64+d]
  l += __shfl_xor(l, 32);
  const float rl = 1.0f / l;
  unsigned short* orow = O + (size_t)(b_ * SEQ + qg) * D_MODEL + h_ * DK;
#pragma unroll
  for (int g = 0; g < 4; ++g) {
    us4v pk0, pk1;
#pragma unroll
    for (int j = 0; j < 4; ++j) {
      pk0[j] = f2bf(o0[4 * g + j] * rl);
      pk1[j] = f2bf(o1[4 * g + j] * rl);
    }
    const int d0 = 8 * g + 4 * hi;
    *(us4v*)&orow[d0] = pk0;
    *(us4v*)&orow[32 + d0] = pk1;
  }
}

// ---------------------------------------------------------------------------
extern "C" void kernel_launch(void* const* d_in, const int* in_sizes, int n_in,
                              void* d_out, int out_size, void* d_ws, size_t ws_size,
                              hipStream_t stream) {
  const float* ctx = (const float*)d_in[0];
  const float* val = (const float*)d_in[1];
  // d_in[2] = mask: statically causal triu(k=1); handled analytically.
  const float* Wq = (const float*)d_in[3];
  const float* bq = (const float*)d_in[4];
  const float* Wk = (const float*)d_in[5];
  const float* bk = (const float*)d_in[6];
  const float* Wv = (const float*)d_in[7];
  const float* bv = (const float*)d_in[8];
  const float* Wo = (const float*)d_in[9];
  const float* bo = (const float*)d_in[10];

  unsigned short* ws = (unsigned short*)d_ws;
  const size_t XSZ = (size_t)BATCH * SEQ * D_MODEL;  // 8388608
  const size_t WSZ = (size_t)D_MODEL * D_MODEL;      // 1048576
  unsigned short* Xc  = ws;                // Xc,Xv adjacent (cvtbf2 target)
  unsigned short* Xv  = Xc + XSZ;
  unsigned short* Wqt = Xv + XSZ;
  unsigned short* Wkt = Wqt + WSZ;
  unsigned short* Wvt = Wkt + WSZ;
  unsigned short* Wot = Wvt + WSZ;
  unsigned short* Qb  = Wot + WSZ;
  unsigned short* Kb  = Qb + XSZ;
  unsigned short* Vtb = Kb + XSZ;
  unsigned short* Ob  = Vtb + XSZ;

  cvtbf2<<<2048, 256, 0, stream>>>(ctx, val, Xc, (int)XSZ);
  wtrans<<<dim3(32, 32, 4), dim3(32, 8), 0, stream>>>(Wq, Wk, Wv, Wo, Wqt, Wkt, Wvt, Wot);

  // merged Q/K/V projections: grid (8, 64, 3)
  gemmQKV<<<dim3(8, 64, 3), 256, 0, stream>>>(Xc, Xv, Wqt, Wkt, Wvt,
                                              bq, bk, bv, Qb, Kb, Vtb);

  // 1024 blocks: x = bh (64, %8 -> XCD locality), y = 16 strips heavy-first
  attn4w<<<dim3(BATCH * NH, 16), 256, 0, stream>>>(Qb, Kb, Vtb, Ob);

  gemmO<<<dim3(8, 64), 256, 0, stream>>>(Ob, Wot, bo, (float*)d_out);
}